// Round 12
// baseline (203.043 us; speedup 1.0000x reference)
//
#include <hip/hip_runtime.h>
#include <math.h>

#define N 4096
#define NFEAT 512
#define NHID 64
#define NCLASS 16
#define NHEADS 8
#define ALPHA 0.2f
#define NC 256   // chunks per head (16 rows each)
#define JSPL 8   // layer-2 j-split
#define JLEN (N / JSPL)

typedef __attribute__((ext_vector_type(8))) short bf16x8;
typedef __attribute__((ext_vector_type(4))) float f32x4;

__device__ inline unsigned short f2bf(float f) {
  unsigned u = __float_as_uint(f);
  unsigned r = u + 0x7fffu + ((u >> 16) & 1u);  // RNE
  return (unsigned short)(r >> 16);
}
__device__ inline float bf2f(unsigned short u) {
  return __uint_as_float(((unsigned)u) << 16);
}
__device__ inline unsigned mono(float f) {
  unsigned u = __float_as_uint(f);
  return (u & 0x80000000u) ? ~u : (u | 0x80000000u);
}
__device__ inline float unmono(unsigned m) {
  return (m >> 31) ? __uint_as_float(m & 0x7FFFFFFFu) : __uint_as_float(~m);
}

// ---------------------------------------------------------------------------
// P0: pack. blocks [0,2048): x->bf16; [2048,2112): Wt=bf16(Wh^T);
// 2112: Wt2 + tmax2 init.
// ---------------------------------------------------------------------------
__global__ __launch_bounds__(256) void k_pack(const float* __restrict__ x,
                                              const float* __restrict__ Wh,
                                              const float* __restrict__ Wo,
                                              unsigned short* __restrict__ xb,
                                              unsigned short* __restrict__ Wt,
                                              unsigned short* __restrict__ Wt2,
                                              unsigned* __restrict__ tmax2u) {
  int b = blockIdx.x;
  if (b < 2048) {
    int i = (b * 256 + threadIdx.x) * 4;
    float4 v = *(const float4*)(x + i);
    ushort4 o;
    o.x = f2bf(v.x); o.y = f2bf(v.y); o.z = f2bf(v.z); o.w = f2bf(v.w);
    *(ushort4*)(xb + i) = o;
  } else if (b < 2112) {
    int idx = b - 2048;
    int kt = idx & 7, hd = idx >> 3;
    __shared__ float ld[64][65];
    const float* src = Wh + ((size_t)hd * NFEAT + kt * 64) * NHID;
    int r = threadIdx.x >> 2, c0 = (threadIdx.x & 3) * 16;
#pragma unroll
    for (int j = 0; j < 4; ++j) {
      float4 v = *(const float4*)(src + (size_t)r * NHID + c0 + j * 4);
      ld[r][c0 + j * 4 + 0] = v.x; ld[r][c0 + j * 4 + 1] = v.y;
      ld[r][c0 + j * 4 + 2] = v.z; ld[r][c0 + j * 4 + 3] = v.w;
    }
    __syncthreads();
    int n = threadIdx.x >> 2, kq = threadIdx.x & 3;
    unsigned short tmp[16];
#pragma unroll
    for (int j = 0; j < 16; ++j) tmp[j] = f2bf(ld[kq * 16 + j][n]);
    unsigned short* dst = Wt + ((size_t)hd * 64 + n) * NFEAT + kt * 64 + kq * 16;
    ((uint4*)dst)[0] = *(uint4*)tmp;
    ((uint4*)dst)[1] = *(uint4*)(tmp + 8);
  } else {
    for (int e = threadIdx.x; e < NFEAT * NCLASS; e += 256) {
      int n = e & 15, k = e >> 4;
      Wt2[(size_t)n * NFEAT + k] = f2bf(Wo[(size_t)k * NCLASS + n]);
    }
    if (threadIdx.x == 0) *tmax2u = 0u;  // mono(-inf)
  }
}

// ---------------------------------------------------------------------------
// K1: MFMA bf16 GEMM h = x @ Wh per head, 128x64 tile, 4 waves, fused scores.
// h stored bf16.
// ---------------------------------------------------------------------------
__global__ __launch_bounds__(256) void k_gemm_h(const unsigned short* __restrict__ xb,
                                                const unsigned short* __restrict__ Wt,
                                                const float* __restrict__ ah,
                                                unsigned short* __restrict__ h1b,
                                                float* __restrict__ ssrc,
                                                float* __restrict__ sdst) {
  const int hd = blockIdx.y;
  const int i0 = blockIdx.x * 128;
  const int t = threadIdx.x;
  const int w = t >> 6, lane = t & 63;
  const int lr = lane & 15, kg = lane >> 4;
  const int wm = (w & 1) * 64, wn = (w >> 1) * 32;
  __shared__ uint4 Als[128][4];
  __shared__ uint4 Bls[64][4];
  __shared__ float sredS[128][2];
  __shared__ float sredD[128][2];
  const unsigned short* xrow = xb + (size_t)i0 * NFEAT;
  const unsigned short* wrow = Wt + (size_t)hd * 64 * NFEAT;

  f32x4 acc[4][2];
#pragma unroll
  for (int a = 0; a < 4; ++a)
#pragma unroll
    for (int b = 0; b < 2; ++b) acc[a][b] = (f32x4){0.f, 0.f, 0.f, 0.f};

  const int ra = t >> 1, ua = (t & 1) * 2;
  const int rb = t >> 2, ub = t & 3;
  for (int k0 = 0; k0 < NFEAT; k0 += 32) {
    uint4 qa0 = *(const uint4*)(xrow + (size_t)ra * NFEAT + k0 + ua * 8);
    uint4 qa1 = *(const uint4*)(xrow + (size_t)ra * NFEAT + k0 + ua * 8 + 8);
    uint4 qb  = *(const uint4*)(wrow + (size_t)rb * NFEAT + k0 + ub * 8);
    Als[ra][(ua) ^ (ra & 3)] = qa0;
    Als[ra][(ua + 1) ^ (ra & 3)] = qa1;
    Bls[rb][ub ^ (rb & 3)] = qb;
    __syncthreads();
    bf16x8 af[4], bfv[2];
#pragma unroll
    for (int mb = 0; mb < 4; ++mb) {
      int row = wm + mb * 16 + lr;
      af[mb] = __builtin_bit_cast(bf16x8, Als[row][kg ^ (row & 3)]);
    }
#pragma unroll
    for (int nb = 0; nb < 2; ++nb) {
      int col = wn + nb * 16 + lr;
      bfv[nb] = __builtin_bit_cast(bf16x8, Bls[col][kg ^ (col & 3)]);
    }
#pragma unroll
    for (int mb = 0; mb < 4; ++mb)
#pragma unroll
      for (int nb = 0; nb < 2; ++nb)
        acc[mb][nb] = __builtin_amdgcn_mfma_f32_16x16x32_bf16(af[mb], bfv[nb], acc[mb][nb], 0, 0, 0);
    __syncthreads();
  }

  unsigned short* hout = h1b + ((size_t)hd * N + i0) * NHID;
#pragma unroll
  for (int mb = 0; mb < 4; ++mb)
#pragma unroll
    for (int nb = 0; nb < 2; ++nb) {
      int rbase = wm + mb * 16 + kg * 4;
      int col = wn + nb * 16 + lr;
#pragma unroll
      for (int reg = 0; reg < 4; ++reg)
        hout[(size_t)(rbase + reg) * NHID + col] = f2bf(acc[mb][nb][reg]);
    }

  float aS[2], aD[2];
#pragma unroll
  for (int nb = 0; nb < 2; ++nb) {
    aS[nb] = ah[hd * 128 + wn + nb * 16 + lr];
    aD[nb] = ah[hd * 128 + 64 + wn + nb * 16 + lr];
  }
#pragma unroll
  for (int mb = 0; mb < 4; ++mb)
#pragma unroll
    for (int reg = 0; reg < 4; ++reg) {
      float ps = acc[mb][0][reg] * aS[0] + acc[mb][1][reg] * aS[1];
      float pd = acc[mb][0][reg] * aD[0] + acc[mb][1][reg] * aD[1];
#pragma unroll
      for (int m = 1; m < 16; m <<= 1) { ps += __shfl_xor(ps, m); pd += __shfl_xor(pd, m); }
      if (lr == 0) {
        int rl = wm + mb * 16 + kg * 4 + reg;
        sredS[rl][w >> 1] = ps;
        sredD[rl][w >> 1] = pd;
      }
    }
  __syncthreads();
  if (t < 128) {
    ssrc[(size_t)hd * N + i0 + t] = sredS[t][0] + sredS[t][1];
    sdst[(size_t)hd * N + i0 + t] = sredD[t][0] + sredD[t][1];
  }
}

// ---------------------------------------------------------------------------
// K4: ballot rank + per-row split-k (layer 1 only). u32 keys.
// ---------------------------------------------------------------------------
__global__ __launch_bounds__(256) void k_rank(const float* __restrict__ t,
                                              const float* __restrict__ ssrc,
                                              float* __restrict__ ts,
                                              int* __restrict__ perm,
                                              int* __restrict__ ksp) {
  int hd = blockIdx.y;
  const float* th = t + (size_t)hd * N;
  __shared__ unsigned skey[N];
  int tid = threadIdx.x;
  for (int i = tid; i < N; i += 256)
    skey[i] = (mono(th[i]) & 0xFFFFF000u) | (unsigned)i;
  __syncthreads();
  int wv = tid >> 6, lane = tid & 63;
  int jbase = blockIdx.x * 64 + wv * 16;
  unsigned kj[16], qk[16];
  int cnt[16], cq[16];
#pragma unroll
  for (int jj = 0; jj < 16; ++jj) {
    kj[jj] = skey[jbase + jj];
    qk[jj] = (mono(-ssrc[(size_t)hd * N + jbase + jj]) & 0xFFFFF000u) | 0xFFFu;
    cnt[jj] = 0; cq[jj] = 0;
  }
  for (int c = 0; c < N; c += 64) {
    unsigned key = skey[c + lane];
#pragma unroll
    for (int jj = 0; jj < 16; ++jj) {
      cnt[jj] += __popcll(__ballot(key < kj[jj]));
      cq[jj]  += __popcll(__ballot(key < qk[jj]));
    }
  }
  int myc = 0, myq = 0;
#pragma unroll
  for (int jj = 0; jj < 16; ++jj)
    if (lane == jj) { myc = cnt[jj]; myq = cq[jj]; }
  if (lane < 16) {
    int j = jbase + lane;
    ts[(size_t)hd * N + myc] = th[j];
    perm[(size_t)hd * N + myc] = j;
    ksp[(size_t)hd * N + j] = myq;
  }
}

// ---------------------------------------------------------------------------
// K5a: chunksum layer 1 (wide grid for the gather). One wave per 16-row
// chunk; grid (64, 8) x 256 thr = 2048 waves.
// ---------------------------------------------------------------------------
__global__ __launch_bounds__(256) void k_chunksum1(const float* __restrict__ ts,
                                                   const int* __restrict__ perm,
                                                   const unsigned short* __restrict__ h1b,
                                                   float* __restrict__ csA,
                                                   float* __restrict__ csB,
                                                   float* __restrict__ csAz,
                                                   float* __restrict__ csBz) {
  int hd = blockIdx.y, lane = threadIdx.x & 63;
  int c = blockIdx.x * 4 + (threadIdx.x >> 6);
  int r0 = c * 16;
  float tm = ts[(size_t)hd * N + N - 1];
  float tvv = ts[(size_t)hd * N + r0 + (lane & 15)];
  float ev = expf((lane < 16 ? ALPHA : 1.f) * (tvv - tm));
  int pvv = perm[(size_t)hd * N + r0 + (lane & 15)];
  float sA = 0.f, sB = 0.f, zA = 0.f, zB = 0.f;
#pragma unroll
  for (int r = 0; r < 16; ++r) {
    float eA = __shfl(ev, r);
    float eB = __shfl(ev, 16 + r);
    int p = __shfl(pvv, r);
    float hv = bf2f(h1b[((size_t)hd * N + p) * NHID + lane]);
    sA += eA * hv; sB += eB * hv; zA += eA; zB += eB;
  }
  csA[((size_t)hd * NC + c) * NHID + lane] = sA;
  csB[((size_t)hd * NC + c) * NHID + lane] = sB;
  if (lane == 0) { csAz[hd * NC + c] = zA; csBz[hd * NC + c] = zB; }
}

// ---------------------------------------------------------------------------
// K5b: scan-only layer 1 (narrow; no gather). 8 blocks x 1024 thr.
// ---------------------------------------------------------------------------
__global__ __launch_bounds__(1024) void k_chunkscan1(float* __restrict__ csA,
                                                     float* __restrict__ csB,
                                                     float* __restrict__ csAz,
                                                     float* __restrict__ csBz) {
  int hd = blockIdx.x;
  int t = threadIdx.x, w = t >> 6, lane = t & 63;
  __shared__ float pA[16][64], pB[16][64];
  __shared__ float pAz[16], pBz[16];
  float rA[16], rB[16], rAz[16], rBz[16];
#pragma unroll
  for (int cc = 0; cc < 16; ++cc) {
    int c = w * 16 + cc;
    rA[cc] = csA[((size_t)hd * NC + c) * NHID + lane];
    rB[cc] = csB[((size_t)hd * NC + c) * NHID + lane];
    rAz[cc] = csAz[hd * NC + c];
    rBz[cc] = csBz[hd * NC + c];
  }
  float tA = 0.f, tB = 0.f, tAz = 0.f, tBz = 0.f;
#pragma unroll
  for (int cc = 0; cc < 16; ++cc) { tA += rA[cc]; tB += rB[cc]; tAz += rAz[cc]; tBz += rBz[cc]; }
  pA[w][lane] = tA; pB[w][lane] = tB;
  if (lane == 0) { pAz[w] = tAz; pBz[w] = tBz; }
  __syncthreads();
  float bA = 0.f, bAz = 0.f, bB = 0.f, bBz = 0.f;
  for (int w2 = 0; w2 < w; ++w2) { bA += pA[w2][lane]; bAz += pAz[w2]; }
  for (int w2 = w + 1; w2 < 16; ++w2) { bB += pB[w2][lane]; bBz += pBz[w2]; }
  float run = bA, runz = bAz;
#pragma unroll
  for (int cc = 0; cc < 16; ++cc) {
    int c = w * 16 + cc;
    csA[((size_t)hd * NC + c) * NHID + lane] = run; run += rA[cc];
    if (lane == 0) csAz[hd * NC + c] = runz;
    runz += rAz[cc];
  }
  run = bB; runz = bBz;
#pragma unroll
  for (int cc = 15; cc >= 0; --cc) {
    int c = w * 16 + cc;
    csB[((size_t)hd * NC + c) * NHID + lane] = run; run += rB[cc];
    if (lane == 0) csBz[hd * NC + c] = runz;
    runz += rBz[cc];
  }
}

// ---------------------------------------------------------------------------
// K6: layer-1 combine. Precomputed split-k; chunk bases + 16-term rebuild.
// ---------------------------------------------------------------------------
__global__ __launch_bounds__(256) void k_combine1(const float* __restrict__ ssrc,
                                                  const float* __restrict__ ts,
                                                  const int* __restrict__ perm,
                                                  const int* __restrict__ ksp,
                                                  const unsigned short* __restrict__ h1b,
                                                  const float* __restrict__ csA,
                                                  const float* __restrict__ csB,
                                                  const float* __restrict__ csAz,
                                                  const float* __restrict__ csBz,
                                                  unsigned short* __restrict__ xcb) {
  int hd = blockIdx.x >> 8;
  int base = (blockIdx.x & 255) * 16;
  int w = threadIdx.x >> 6, lane = threadIdx.x & 63;
  const float* tsh = ts + (size_t)hd * N;
  float tm = tsh[N - 1];
  for (int it = 0; it < 4; ++it) {
    int i = base + w * 4 + it;
    float s = ssrc[(size_t)hd * N + i];
    int k = ksp[(size_t)hd * N + i];
    int c = k >> 4; if (c > NC - 1) c = NC - 1;
    int c0 = c * 16;
    float v = s + tm;
    float m = fmaxf(v, ALPHA * v);
    float wA = expf(ALPHA * v - m), wB = expf(v - m);
    size_t cb = (size_t)hd * NC + c;
    float numA = csA[cb * NHID + lane];
    float numB = csB[cb * NHID + lane];
    float zA = csAz[cb], zB = csBz[cb];
    int r15 = lane & 15;
    float tvv = tsh[c0 + r15];
    int pvv = perm[(size_t)hd * N + c0 + r15];
    float ev = expf(((c0 + r15) < k ? ALPHA : 1.f) * (tvv - tm));
#pragma unroll
    for (int r = 0; r < 16; ++r) {
      float e = __shfl(ev, r);
      int p = __shfl(pvv, r);
      float hv = bf2f(h1b[((size_t)hd * N + p) * NHID + lane]);
      bool isA = (c0 + r) < k;
      if (isA) { numA += e * hv; zA += e; } else { numB += e * hv; zB += e; }
    }
    float Z = wA * zA + wB * zB;
    float f = (wA * numA + wB * numB) / Z;
    float e2 = f > 0.f ? f : expf(f) - 1.f;
    xcb[(size_t)i * (NHEADS * NHID) + hd * NHID + lane] = f2bf(e2);
  }
}

// ---------------------------------------------------------------------------
// K7: h2 = xc @ Wo via MFMA + fused layer-2 scores + deterministic global
// tmax (block LDS reduce -> one atomicMax of monotone bits).
// ---------------------------------------------------------------------------
__global__ __launch_bounds__(256) void k_gemm2(const unsigned short* __restrict__ xcb,
                                               const unsigned short* __restrict__ Wt2,
                                               const float* __restrict__ ao,
                                               float* __restrict__ h2,
                                               float* __restrict__ ssrc,
                                               float* __restrict__ sdst,
                                               unsigned* __restrict__ tmax2u) {
  const int t = threadIdx.x;
  const int w = t >> 6, lane = t & 63;
  const int lr = lane & 15, kg = lane >> 4;
  const int i0 = blockIdx.x * 64 + w * 16;
  __shared__ float sd[64];
  f32x4 acc = (f32x4){0.f, 0.f, 0.f, 0.f};
  const unsigned short* arow = xcb + (size_t)(i0 + lr) * NFEAT;
  const unsigned short* brow = Wt2 + (size_t)lr * NFEAT;
#pragma unroll
  for (int k0 = 0; k0 < NFEAT; k0 += 32) {
    bf16x8 af = __builtin_bit_cast(bf16x8, *(const uint4*)(arow + k0 + kg * 8));
    bf16x8 bv = __builtin_bit_cast(bf16x8, *(const uint4*)(brow + k0 + kg * 8));
    acc = __builtin_amdgcn_mfma_f32_16x16x32_bf16(af, bv, acc, 0, 0, 0);
  }
  float aS = ao[lr], aD = ao[16 + lr];
#pragma unroll
  for (int reg = 0; reg < 4; ++reg) {
    int row = i0 + kg * 4 + reg;
    h2[(size_t)row * NCLASS + lr] = acc[reg];
    float ps = acc[reg] * aS, pd = acc[reg] * aD;
#pragma unroll
    for (int m = 1; m < 16; m <<= 1) { ps += __shfl_xor(ps, m); pd += __shfl_xor(pd, m); }
    if (lr == 0) {
      ssrc[row] = ps;
      sdst[row] = pd;
      sd[w * 16 + kg * 4 + reg] = pd;
    }
  }
  __syncthreads();
  if (t < 64) {
    float v = sd[t];
#pragma unroll
    for (int m = 32; m; m >>= 1) v = fmaxf(v, __shfl_xor(v, m));
    if (t == 0) atomicMax(tmax2u, mono(v));
  }
}

// ---------------------------------------------------------------------------
// K8a: layer-2 direct attention PARTIALS. grid (256 row-blocks, JSPL=8
// j-slices) x 128 thr (2 waves, 8 rows/wave). Each block: 16 rows x 512 js.
// ---------------------------------------------------------------------------
__global__ __launch_bounds__(128) void k_attn2p(const float* __restrict__ ssrc,
                                                const float* __restrict__ t,
                                                const float* __restrict__ h2,
                                                const unsigned* __restrict__ tmax2u,
                                                float* __restrict__ pnum,
                                                float* __restrict__ pz) {
  __shared__ float tl[JLEN];  // 2 KB
  int tid = threadIdx.x;
  int jb = blockIdx.y;
  {
    int i4 = tid * 4;
    *(float4*)(tl + i4) = *(const float4*)(t + jb * JLEN + i4);
  }
  __syncthreads();
  int w = tid >> 6, lane = tid & 63;
  int ib = blockIdx.x * 16 + w * 8;
  float tmax = unmono(*tmax2u);
  float s[8], rowm[8], Z[8];
  float num[8][16];
#pragma unroll
  for (int r = 0; r < 8; ++r) {
    s[r] = ssrc[ib + r];
    float v = s[r] + tmax;
    rowm[r] = fmaxf(v, ALPHA * v);  // exact global row max (monotone LR)
    Z[r] = 0.f;
#pragma unroll
    for (int c = 0; c < 16; ++c) num[r][c] = 0.f;
  }
  for (int jj = lane; jj < JLEN; jj += 64) {
    float tj = tl[jj];
    const float4* hr = (const float4*)(h2 + (size_t)(jb * JLEN + jj) * NCLASS);
    float4 a = hr[0], b = hr[1], c4 = hr[2], d = hr[3];
#pragma unroll
    for (int r = 0; r < 8; ++r) {
      float v = s[r] + tj;
      float e = expf(fmaxf(v, ALPHA * v) - rowm[r]);
      Z[r] += e;
      num[r][0]  += e * a.x;  num[r][1]  += e * a.y;
      num[r][2]  += e * a.z;  num[r][3]  += e * a.w;
      num[r][4]  += e * b.x;  num[r][5]  += e * b.y;
      num[r][6]  += e * b.z;  num[r][7]  += e * b.w;
      num[r][8]  += e * c4.x; num[r][9]  += e * c4.y;
      num[r][10] += e * c4.z; num[r][11] += e * c4.w;
      num[r][12] += e * d.x;  num[r][13] += e * d.y;
      num[r][14] += e * d.z;  num[r][15] += e * d.w;
    }
  }
#pragma unroll
  for (int m = 32; m; m >>= 1) {
#pragma unroll
    for (int r = 0; r < 8; ++r) {
      Z[r] += __shfl_xor(Z[r], m);
#pragma unroll
      for (int c = 0; c < 16; ++c) num[r][c] += __shfl_xor(num[r][c], m);
    }
  }
#pragma unroll
  for (int r = 0; r < 8; ++r) {
    float ov = 0.f;
#pragma unroll
    for (int c = 0; c < 16; ++c) if (lane == c) ov = num[r][c];  // static select
    if (lane < 16) pnum[((size_t)jb * N + ib + r) * NCLASS + lane] = ov;
    if (lane == 16) pz[(size_t)jb * N + ib + r] = Z[r];
  }
}

// ---------------------------------------------------------------------------
// K8b: combine partials + ELU + log_softmax. 256 blocks x 256 thr
// (16 rows/block, 16 lanes/row).
// ---------------------------------------------------------------------------
__global__ __launch_bounds__(256) void k_attn2f(const float* __restrict__ pnum,
                                                const float* __restrict__ pz,
                                                float* __restrict__ out) {
  int g = threadIdx.x >> 4, cl = threadIdx.x & 15;
  int i = blockIdx.x * 16 + g;
  float nsum = 0.f, zsum = 0.f;
#pragma unroll
  for (int jb = 0; jb < JSPL; ++jb) {
    nsum += pnum[((size_t)jb * N + i) * NCLASS + cl];
    zsum += pz[(size_t)jb * N + i];
  }
  float o = nsum / zsum;
  o = o > 0.f ? o : expf(o) - 1.f;  // ELU
  float mo = o;
#pragma unroll
  for (int mk = 1; mk < 16; mk <<= 1) mo = fmaxf(mo, __shfl_xor(mo, mk, 16));
  float sum = expf(o - mo);
#pragma unroll
  for (int mk = 1; mk < 16; mk <<= 1) sum += __shfl_xor(sum, mk, 16);
  out[(size_t)i * NCLASS + cl] = o - mo - logf(sum);
}

// ---------------------------------------------------------------------------
extern "C" void kernel_launch(void* const* d_in, const int* in_sizes, int n_in,
                              void* d_out, int out_size, void* d_ws, size_t ws_size,
                              hipStream_t stream) {
  const float* x  = (const float*)d_in[0];
  const float* Wh = (const float*)d_in[1];
  const float* ah = (const float*)d_in[2];
  const float* Wo = (const float*)d_in[3];
  const float* ao = (const float*)d_in[4];
  float* out = (float*)d_out;

  char* base = (char*)d_ws;
  size_t off = 0;
  auto alloc_f = [&](size_t n) -> float* {
    float* p = (float*)(base + off);
    off = (off + n * sizeof(float) + 255) & ~(size_t)255;
    return p;
  };
  auto alloc_i = [&](size_t n) -> int* {
    int* p = (int*)(base + off);
    off = (off + n * sizeof(int) + 255) & ~(size_t)255;
    return p;
  };
  auto alloc_u16 = [&](size_t n) -> unsigned short* {
    unsigned short* p = (unsigned short*)(base + off);
    off = (off + n * sizeof(unsigned short) + 255) & ~(size_t)255;
    return p;
  };

  unsigned short* xbf = alloc_u16((size_t)N * NFEAT);
  unsigned short* Wt  = alloc_u16((size_t)NHEADS * NHID * NFEAT);
  unsigned short* Wt2 = alloc_u16((size_t)NCLASS * NFEAT);
  unsigned short* h1b = alloc_u16((size_t)NHEADS * N * NHID);
  float* ssrc1 = alloc_f((size_t)NHEADS * N);
  float* sdst1 = alloc_f((size_t)NHEADS * N);
  float* ts1   = alloc_f((size_t)NHEADS * N);
  int*   perm1 = alloc_i((size_t)NHEADS * N);
  int*   ksp1  = alloc_i((size_t)NHEADS * N);
  float* csA1  = alloc_f((size_t)NHEADS * NC * NHID);
  float* csB1  = alloc_f((size_t)NHEADS * NC * NHID);
  float* csAz1 = alloc_f(NHEADS * NC);
  float* csBz1 = alloc_f(NHEADS * NC);
  unsigned short* xcb = alloc_u16((size_t)N * NHEADS * NHID);
  float* h2    = alloc_f((size_t)N * NCLASS);
  float* ssrc2 = alloc_f(N);
  float* sdst2 = alloc_f(N);
  unsigned* tmax2u = (unsigned*)alloc_i(1);
  float* pnum  = alloc_f((size_t)JSPL * N * NCLASS);
  float* pz    = alloc_f((size_t)JSPL * N);

  if (off > ws_size) return;

  hipLaunchKernelGGL(k_pack, dim3(2113), dim3(256), 0, stream, x, Wh, Wo, xbf, Wt, Wt2, tmax2u);

  // ---- Layer 1 ----
  hipLaunchKernelGGL(k_gemm_h, dim3(N / 128, NHEADS), dim3(256), 0, stream, xbf, Wt, ah, h1b, ssrc1, sdst1);
  hipLaunchKernelGGL(k_rank, dim3(64, NHEADS), dim3(256), 0, stream, sdst1, ssrc1, ts1, perm1, ksp1);
  hipLaunchKernelGGL(k_chunksum1, dim3(64, NHEADS), dim3(256), 0, stream, ts1, perm1, h1b, csA1, csB1, csAz1, csBz1);
  hipLaunchKernelGGL(k_chunkscan1, dim3(NHEADS), dim3(1024), 0, stream, csA1, csB1, csAz1, csBz1);
  hipLaunchKernelGGL(k_combine1, dim3(NHEADS * 256), dim3(256), 0, stream, ssrc1, ts1, perm1, ksp1, h1b, csA1, csB1, csAz1, csBz1, xcb);

  // ---- Layer 2 (direct attention, j-split partials) ----
  hipLaunchKernelGGL(k_gemm2, dim3(N / 64), dim3(256), 0, stream, xcb, Wt2, ao, h2, ssrc2, sdst2, tmax2u);
  hipLaunchKernelGGL(k_attn2p, dim3(N / 16, JSPL), dim3(128), 0, stream, ssrc2, sdst2, h2, tmax2u, pnum, pz);
  hipLaunchKernelGGL(k_attn2f, dim3(N / 16), dim3(256), 0, stream, pnum, pz, out);
}

// Round 13
// 133.378 us; speedup vs baseline: 1.5223x; 1.5223x over previous
//
#include <hip/hip_runtime.h>
#include <math.h>

#define N 4096
#define NFEAT 512
#define NHID 64
#define NCLASS 16
#define NHEADS 8
#define ALPHA 0.2f
#define NC 256   // chunks per head (16 rows each)
#define JSPL 4   // layer-2 j-split
#define JLEN (N / JSPL)

typedef __attribute__((ext_vector_type(8))) short bf16x8;
typedef __attribute__((ext_vector_type(4))) float f32x4;

__device__ inline unsigned short f2bf(float f) {
  unsigned u = __float_as_uint(f);
  unsigned r = u + 0x7fffu + ((u >> 16) & 1u);  // RNE
  return (unsigned short)(r >> 16);
}
__device__ inline float bf2f(unsigned short u) {
  return __uint_as_float(((unsigned)u) << 16);
}
__device__ inline unsigned mono(float f) {
  unsigned u = __float_as_uint(f);
  return (u & 0x80000000u) ? ~u : (u | 0x80000000u);
}
__device__ inline float unmono(unsigned m) {
  return (m >> 31) ? __uint_as_float(m & 0x7FFFFFFFu) : __uint_as_float(~m);
}

// ---------------------------------------------------------------------------
// P0: pack. blocks [0,2048): x->bf16; [2048,2112): Wt=bf16(Wh^T);
// 2112: Wt2 + tmax2 init.
// ---------------------------------------------------------------------------
__global__ __launch_bounds__(256) void k_pack(const float* __restrict__ x,
                                              const float* __restrict__ Wh,
                                              const float* __restrict__ Wo,
                                              unsigned short* __restrict__ xb,
                                              unsigned short* __restrict__ Wt,
                                              unsigned short* __restrict__ Wt2,
                                              unsigned* __restrict__ tmax2u) {
  int b = blockIdx.x;
  if (b < 2048) {
    int i = (b * 256 + threadIdx.x) * 4;
    float4 v = *(const float4*)(x + i);
    ushort4 o;
    o.x = f2bf(v.x); o.y = f2bf(v.y); o.z = f2bf(v.z); o.w = f2bf(v.w);
    *(ushort4*)(xb + i) = o;
  } else if (b < 2112) {
    int idx = b - 2048;
    int kt = idx & 7, hd = idx >> 3;
    __shared__ float ld[64][65];
    const float* src = Wh + ((size_t)hd * NFEAT + kt * 64) * NHID;
    int r = threadIdx.x >> 2, c0 = (threadIdx.x & 3) * 16;
#pragma unroll
    for (int j = 0; j < 4; ++j) {
      float4 v = *(const float4*)(src + (size_t)r * NHID + c0 + j * 4);
      ld[r][c0 + j * 4 + 0] = v.x; ld[r][c0 + j * 4 + 1] = v.y;
      ld[r][c0 + j * 4 + 2] = v.z; ld[r][c0 + j * 4 + 3] = v.w;
    }
    __syncthreads();
    int n = threadIdx.x >> 2, kq = threadIdx.x & 3;
    unsigned short tmp[16];
#pragma unroll
    for (int j = 0; j < 16; ++j) tmp[j] = f2bf(ld[kq * 16 + j][n]);
    unsigned short* dst = Wt + ((size_t)hd * 64 + n) * NFEAT + kt * 64 + kq * 16;
    ((uint4*)dst)[0] = *(uint4*)tmp;
    ((uint4*)dst)[1] = *(uint4*)(tmp + 8);
  } else {
    for (int e = threadIdx.x; e < NFEAT * NCLASS; e += 256) {
      int n = e & 15, k = e >> 4;
      Wt2[(size_t)n * NFEAT + k] = f2bf(Wo[(size_t)k * NCLASS + n]);
    }
    if (threadIdx.x == 0) *tmax2u = 0u;  // mono(-inf)
  }
}

// ---------------------------------------------------------------------------
// K1: MFMA bf16 GEMM h = x @ Wh per head, 128x64 tile, 4 waves, fused scores.
// h stored bf16.
// ---------------------------------------------------------------------------
__global__ __launch_bounds__(256) void k_gemm_h(const unsigned short* __restrict__ xb,
                                                const unsigned short* __restrict__ Wt,
                                                const float* __restrict__ ah,
                                                unsigned short* __restrict__ h1b,
                                                float* __restrict__ ssrc,
                                                float* __restrict__ sdst) {
  const int hd = blockIdx.y;
  const int i0 = blockIdx.x * 128;
  const int t = threadIdx.x;
  const int w = t >> 6, lane = t & 63;
  const int lr = lane & 15, kg = lane >> 4;
  const int wm = (w & 1) * 64, wn = (w >> 1) * 32;
  __shared__ uint4 Als[128][4];
  __shared__ uint4 Bls[64][4];
  __shared__ float sredS[128][2];
  __shared__ float sredD[128][2];
  const unsigned short* xrow = xb + (size_t)i0 * NFEAT;
  const unsigned short* wrow = Wt + (size_t)hd * 64 * NFEAT;

  f32x4 acc[4][2];
#pragma unroll
  for (int a = 0; a < 4; ++a)
#pragma unroll
    for (int b = 0; b < 2; ++b) acc[a][b] = (f32x4){0.f, 0.f, 0.f, 0.f};

  const int ra = t >> 1, ua = (t & 1) * 2;
  const int rb = t >> 2, ub = t & 3;
  for (int k0 = 0; k0 < NFEAT; k0 += 32) {
    uint4 qa0 = *(const uint4*)(xrow + (size_t)ra * NFEAT + k0 + ua * 8);
    uint4 qa1 = *(const uint4*)(xrow + (size_t)ra * NFEAT + k0 + ua * 8 + 8);
    uint4 qb  = *(const uint4*)(wrow + (size_t)rb * NFEAT + k0 + ub * 8);
    Als[ra][(ua) ^ (ra & 3)] = qa0;
    Als[ra][(ua + 1) ^ (ra & 3)] = qa1;
    Bls[rb][ub ^ (rb & 3)] = qb;
    __syncthreads();
    bf16x8 af[4], bfv[2];
#pragma unroll
    for (int mb = 0; mb < 4; ++mb) {
      int row = wm + mb * 16 + lr;
      af[mb] = __builtin_bit_cast(bf16x8, Als[row][kg ^ (row & 3)]);
    }
#pragma unroll
    for (int nb = 0; nb < 2; ++nb) {
      int col = wn + nb * 16 + lr;
      bfv[nb] = __builtin_bit_cast(bf16x8, Bls[col][kg ^ (col & 3)]);
    }
#pragma unroll
    for (int mb = 0; mb < 4; ++mb)
#pragma unroll
      for (int nb = 0; nb < 2; ++nb)
        acc[mb][nb] = __builtin_amdgcn_mfma_f32_16x16x32_bf16(af[mb], bfv[nb], acc[mb][nb], 0, 0, 0);
    __syncthreads();
  }

  unsigned short* hout = h1b + ((size_t)hd * N + i0) * NHID;
#pragma unroll
  for (int mb = 0; mb < 4; ++mb)
#pragma unroll
    for (int nb = 0; nb < 2; ++nb) {
      int rbase = wm + mb * 16 + kg * 4;
      int col = wn + nb * 16 + lr;
#pragma unroll
      for (int reg = 0; reg < 4; ++reg)
        hout[(size_t)(rbase + reg) * NHID + col] = f2bf(acc[mb][nb][reg]);
    }

  float aS[2], aD[2];
#pragma unroll
  for (int nb = 0; nb < 2; ++nb) {
    aS[nb] = ah[hd * 128 + wn + nb * 16 + lr];
    aD[nb] = ah[hd * 128 + 64 + wn + nb * 16 + lr];
  }
#pragma unroll
  for (int mb = 0; mb < 4; ++mb)
#pragma unroll
    for (int reg = 0; reg < 4; ++reg) {
      float ps = acc[mb][0][reg] * aS[0] + acc[mb][1][reg] * aS[1];
      float pd = acc[mb][0][reg] * aD[0] + acc[mb][1][reg] * aD[1];
#pragma unroll
      for (int m = 1; m < 16; m <<= 1) { ps += __shfl_xor(ps, m); pd += __shfl_xor(pd, m); }
      if (lr == 0) {
        int rl = wm + mb * 16 + kg * 4 + reg;
        sredS[rl][w >> 1] = ps;
        sredD[rl][w >> 1] = pd;
      }
    }
  __syncthreads();
  if (t < 128) {
    ssrc[(size_t)hd * N + i0 + t] = sredS[t][0] + sredS[t][1];
    sdst[(size_t)hd * N + i0 + t] = sredD[t][0] + sredD[t][1];
  }
}

// ---------------------------------------------------------------------------
// K4: ballot rank + per-row split-k (layer 1 only). u32 keys.
// ---------------------------------------------------------------------------
__global__ __launch_bounds__(256) void k_rank(const float* __restrict__ t,
                                              const float* __restrict__ ssrc,
                                              float* __restrict__ ts,
                                              int* __restrict__ perm,
                                              int* __restrict__ ksp) {
  int hd = blockIdx.y;
  const float* th = t + (size_t)hd * N;
  __shared__ unsigned skey[N];
  int tid = threadIdx.x;
  for (int i = tid; i < N; i += 256)
    skey[i] = (mono(th[i]) & 0xFFFFF000u) | (unsigned)i;
  __syncthreads();
  int wv = tid >> 6, lane = tid & 63;
  int jbase = blockIdx.x * 64 + wv * 16;
  unsigned kj[16], qk[16];
  int cnt[16], cq[16];
#pragma unroll
  for (int jj = 0; jj < 16; ++jj) {
    kj[jj] = skey[jbase + jj];
    qk[jj] = (mono(-ssrc[(size_t)hd * N + jbase + jj]) & 0xFFFFF000u) | 0xFFFu;
    cnt[jj] = 0; cq[jj] = 0;
  }
  for (int c = 0; c < N; c += 64) {
    unsigned key = skey[c + lane];
#pragma unroll
    for (int jj = 0; jj < 16; ++jj) {
      cnt[jj] += __popcll(__ballot(key < kj[jj]));
      cq[jj]  += __popcll(__ballot(key < qk[jj]));
    }
  }
  int myc = 0, myq = 0;
#pragma unroll
  for (int jj = 0; jj < 16; ++jj)
    if (lane == jj) { myc = cnt[jj]; myq = cq[jj]; }
  if (lane < 16) {
    int j = jbase + lane;
    ts[(size_t)hd * N + myc] = th[j];
    perm[(size_t)hd * N + myc] = j;
    ksp[(size_t)hd * N + j] = myq;
  }
}

// ---------------------------------------------------------------------------
// K5a: chunksum layer 1 (wide grid for the gather). One wave per 16-row
// chunk; grid (64, 8) x 256 thr = 2048 waves.
// ---------------------------------------------------------------------------
__global__ __launch_bounds__(256) void k_chunksum1(const float* __restrict__ ts,
                                                   const int* __restrict__ perm,
                                                   const unsigned short* __restrict__ h1b,
                                                   float* __restrict__ csA,
                                                   float* __restrict__ csB,
                                                   float* __restrict__ csAz,
                                                   float* __restrict__ csBz) {
  int hd = blockIdx.y, lane = threadIdx.x & 63;
  int c = blockIdx.x * 4 + (threadIdx.x >> 6);
  int r0 = c * 16;
  float tm = ts[(size_t)hd * N + N - 1];
  float tvv = ts[(size_t)hd * N + r0 + (lane & 15)];
  float ev = expf((lane < 16 ? ALPHA : 1.f) * (tvv - tm));
  int pvv = perm[(size_t)hd * N + r0 + (lane & 15)];
  float sA = 0.f, sB = 0.f, zA = 0.f, zB = 0.f;
#pragma unroll
  for (int r = 0; r < 16; ++r) {
    float eA = __shfl(ev, r);
    float eB = __shfl(ev, 16 + r);
    int p = __shfl(pvv, r);
    float hv = bf2f(h1b[((size_t)hd * N + p) * NHID + lane]);
    sA += eA * hv; sB += eB * hv; zA += eA; zB += eB;
  }
  csA[((size_t)hd * NC + c) * NHID + lane] = sA;
  csB[((size_t)hd * NC + c) * NHID + lane] = sB;
  if (lane == 0) { csAz[hd * NC + c] = zA; csBz[hd * NC + c] = zB; }
}

// ---------------------------------------------------------------------------
// K5b: scan-only layer 1 (narrow; no gather). 8 blocks x 1024 thr.
// ---------------------------------------------------------------------------
__global__ __launch_bounds__(1024) void k_chunkscan1(float* __restrict__ csA,
                                                     float* __restrict__ csB,
                                                     float* __restrict__ csAz,
                                                     float* __restrict__ csBz) {
  int hd = blockIdx.x;
  int t = threadIdx.x, w = t >> 6, lane = t & 63;
  __shared__ float pA[16][64], pB[16][64];
  __shared__ float pAz[16], pBz[16];
  float rA[16], rB[16], rAz[16], rBz[16];
#pragma unroll
  for (int cc = 0; cc < 16; ++cc) {
    int c = w * 16 + cc;
    rA[cc] = csA[((size_t)hd * NC + c) * NHID + lane];
    rB[cc] = csB[((size_t)hd * NC + c) * NHID + lane];
    rAz[cc] = csAz[hd * NC + c];
    rBz[cc] = csBz[hd * NC + c];
  }
  float tA = 0.f, tB = 0.f, tAz = 0.f, tBz = 0.f;
#pragma unroll
  for (int cc = 0; cc < 16; ++cc) { tA += rA[cc]; tB += rB[cc]; tAz += rAz[cc]; tBz += rBz[cc]; }
  pA[w][lane] = tA; pB[w][lane] = tB;
  if (lane == 0) { pAz[w] = tAz; pBz[w] = tBz; }
  __syncthreads();
  float bA = 0.f, bAz = 0.f, bB = 0.f, bBz = 0.f;
  for (int w2 = 0; w2 < w; ++w2) { bA += pA[w2][lane]; bAz += pAz[w2]; }
  for (int w2 = w + 1; w2 < 16; ++w2) { bB += pB[w2][lane]; bBz += pBz[w2]; }
  float run = bA, runz = bAz;
#pragma unroll
  for (int cc = 0; cc < 16; ++cc) {
    int c = w * 16 + cc;
    csA[((size_t)hd * NC + c) * NHID + lane] = run; run += rA[cc];
    if (lane == 0) csAz[hd * NC + c] = runz;
    runz += rAz[cc];
  }
  run = bB; runz = bBz;
#pragma unroll
  for (int cc = 15; cc >= 0; --cc) {
    int c = w * 16 + cc;
    csB[((size_t)hd * NC + c) * NHID + lane] = run; run += rB[cc];
    if (lane == 0) csBz[hd * NC + c] = runz;
    runz += rBz[cc];
  }
}

// ---------------------------------------------------------------------------
// K6: layer-1 combine. Precomputed split-k; chunk bases + 16-term rebuild.
// ---------------------------------------------------------------------------
__global__ __launch_bounds__(256) void k_combine1(const float* __restrict__ ssrc,
                                                  const float* __restrict__ ts,
                                                  const int* __restrict__ perm,
                                                  const int* __restrict__ ksp,
                                                  const unsigned short* __restrict__ h1b,
                                                  const float* __restrict__ csA,
                                                  const float* __restrict__ csB,
                                                  const float* __restrict__ csAz,
                                                  const float* __restrict__ csBz,
                                                  unsigned short* __restrict__ xcb) {
  int hd = blockIdx.x >> 8;
  int base = (blockIdx.x & 255) * 16;
  int w = threadIdx.x >> 6, lane = threadIdx.x & 63;
  const float* tsh = ts + (size_t)hd * N;
  float tm = tsh[N - 1];
  for (int it = 0; it < 4; ++it) {
    int i = base + w * 4 + it;
    float s = ssrc[(size_t)hd * N + i];
    int k = ksp[(size_t)hd * N + i];
    int c = k >> 4; if (c > NC - 1) c = NC - 1;
    int c0 = c * 16;
    float v = s + tm;
    float m = fmaxf(v, ALPHA * v);
    float wA = expf(ALPHA * v - m), wB = expf(v - m);
    size_t cb = (size_t)hd * NC + c;
    float numA = csA[cb * NHID + lane];
    float numB = csB[cb * NHID + lane];
    float zA = csAz[cb], zB = csBz[cb];
    int r15 = lane & 15;
    float tvv = tsh[c0 + r15];
    int pvv = perm[(size_t)hd * N + c0 + r15];
    float ev = expf(((c0 + r15) < k ? ALPHA : 1.f) * (tvv - tm));
#pragma unroll
    for (int r = 0; r < 16; ++r) {
      float e = __shfl(ev, r);
      int p = __shfl(pvv, r);
      float hv = bf2f(h1b[((size_t)hd * N + p) * NHID + lane]);
      bool isA = (c0 + r) < k;
      if (isA) { numA += e * hv; zA += e; } else { numB += e * hv; zB += e; }
    }
    float Z = wA * zA + wB * zB;
    float f = (wA * numA + wB * numB) / Z;
    float e2 = f > 0.f ? f : expf(f) - 1.f;
    xcb[(size_t)i * (NHEADS * NHID) + hd * NHID + lane] = f2bf(e2);
  }
}

// ---------------------------------------------------------------------------
// K7: h2 = xc @ Wo via MFMA + fused layer-2 scores + deterministic global
// tmax (block LDS reduce -> one atomicMax of monotone bits).
// ---------------------------------------------------------------------------
__global__ __launch_bounds__(256) void k_gemm2(const unsigned short* __restrict__ xcb,
                                               const unsigned short* __restrict__ Wt2,
                                               const float* __restrict__ ao,
                                               float* __restrict__ h2,
                                               float* __restrict__ ssrc,
                                               float* __restrict__ sdst,
                                               unsigned* __restrict__ tmax2u) {
  const int t = threadIdx.x;
  const int w = t >> 6, lane = t & 63;
  const int lr = lane & 15, kg = lane >> 4;
  const int i0 = blockIdx.x * 64 + w * 16;
  __shared__ float sd[64];
  f32x4 acc = (f32x4){0.f, 0.f, 0.f, 0.f};
  const unsigned short* arow = xcb + (size_t)(i0 + lr) * NFEAT;
  const unsigned short* brow = Wt2 + (size_t)lr * NFEAT;
#pragma unroll
  for (int k0 = 0; k0 < NFEAT; k0 += 32) {
    bf16x8 af = __builtin_bit_cast(bf16x8, *(const uint4*)(arow + k0 + kg * 8));
    bf16x8 bv = __builtin_bit_cast(bf16x8, *(const uint4*)(brow + k0 + kg * 8));
    acc = __builtin_amdgcn_mfma_f32_16x16x32_bf16(af, bv, acc, 0, 0, 0);
  }
  float aS = ao[lr], aD = ao[16 + lr];
#pragma unroll
  for (int reg = 0; reg < 4; ++reg) {
    int row = i0 + kg * 4 + reg;
    h2[(size_t)row * NCLASS + lr] = acc[reg];
    float ps = acc[reg] * aS, pd = acc[reg] * aD;
#pragma unroll
    for (int m = 1; m < 16; m <<= 1) { ps += __shfl_xor(ps, m); pd += __shfl_xor(pd, m); }
    if (lr == 0) {
      ssrc[row] = ps;
      sdst[row] = pd;
      sd[w * 16 + kg * 4 + reg] = pd;
    }
  }
  __syncthreads();
  if (t < 64) {
    float v = sd[t];
#pragma unroll
    for (int m = 32; m; m >>= 1) v = fmaxf(v, __shfl_xor(v, m));
    if (t == 0) atomicMax(tmax2u, mono(v));
  }
}

// ---------------------------------------------------------------------------
// K8a: layer-2 direct attention PARTIALS, R=4 rows/wave (num[4][16]=64 VGPR,
// fits without spill). grid (512 row-blocks, JSPL=4) x 128 thr.
// Each block: 8 rows x 1024 js.
// ---------------------------------------------------------------------------
__global__ __launch_bounds__(128) void k_attn2p(const float* __restrict__ ssrc,
                                                const float* __restrict__ t,
                                                const float* __restrict__ h2,
                                                const unsigned* __restrict__ tmax2u,
                                                float* __restrict__ pnum,
                                                float* __restrict__ pz) {
  __shared__ float tl[JLEN];  // 4 KB
  int tid = threadIdx.x;
  int jb = blockIdx.y;
#pragma unroll
  for (int rep = 0; rep < 2; ++rep) {
    int i4 = (rep * 128 + tid) * 4;
    *(float4*)(tl + i4) = *(const float4*)(t + jb * JLEN + i4);
  }
  __syncthreads();
  int w = tid >> 6, lane = tid & 63;
  int ib = blockIdx.x * 8 + w * 4;
  float tmax = unmono(*tmax2u);
  float s[4], rowm[4], Z[4];
  float num[4][16];
#pragma unroll
  for (int r = 0; r < 4; ++r) {
    s[r] = ssrc[ib + r];
    float v = s[r] + tmax;
    rowm[r] = fmaxf(v, ALPHA * v);  // exact global row max (monotone LR)
    Z[r] = 0.f;
#pragma unroll
    for (int c = 0; c < 16; ++c) num[r][c] = 0.f;
  }
  for (int jj = lane; jj < JLEN; jj += 64) {
    float tj = tl[jj];
    const float4* hr = (const float4*)(h2 + (size_t)(jb * JLEN + jj) * NCLASS);
    float4 a = hr[0], b = hr[1], c4 = hr[2], d = hr[3];
#pragma unroll
    for (int r = 0; r < 4; ++r) {
      float v = s[r] + tj;
      float e = expf(fmaxf(v, ALPHA * v) - rowm[r]);
      Z[r] += e;
      num[r][0]  += e * a.x;  num[r][1]  += e * a.y;
      num[r][2]  += e * a.z;  num[r][3]  += e * a.w;
      num[r][4]  += e * b.x;  num[r][5]  += e * b.y;
      num[r][6]  += e * b.z;  num[r][7]  += e * b.w;
      num[r][8]  += e * c4.x; num[r][9]  += e * c4.y;
      num[r][10] += e * c4.z; num[r][11] += e * c4.w;
      num[r][12] += e * d.x;  num[r][13] += e * d.y;
      num[r][14] += e * d.z;  num[r][15] += e * d.w;
    }
  }
#pragma unroll
  for (int m = 32; m; m >>= 1) {
#pragma unroll
    for (int r = 0; r < 4; ++r) {
      Z[r] += __shfl_xor(Z[r], m);
#pragma unroll
      for (int c = 0; c < 16; ++c) num[r][c] += __shfl_xor(num[r][c], m);
    }
  }
#pragma unroll
  for (int r = 0; r < 4; ++r) {
    float ov = 0.f;
#pragma unroll
    for (int c = 0; c < 16; ++c) if (lane == c) ov = num[r][c];  // static select
    if (lane < 16) pnum[((size_t)jb * N + ib + r) * NCLASS + lane] = ov;
    if (lane == 16) pz[(size_t)jb * N + ib + r] = Z[r];
  }
}

// ---------------------------------------------------------------------------
// K8b: combine partials + ELU + log_softmax. 256 blocks x 256 thr
// (16 rows/block, 16 lanes/row).
// ---------------------------------------------------------------------------
__global__ __launch_bounds__(256) void k_attn2f(const float* __restrict__ pnum,
                                                const float* __restrict__ pz,
                                                float* __restrict__ out) {
  int g = threadIdx.x >> 4, cl = threadIdx.x & 15;
  int i = blockIdx.x * 16 + g;
  float nsum = 0.f, zsum = 0.f;
#pragma unroll
  for (int jb = 0; jb < JSPL; ++jb) {
    nsum += pnum[((size_t)jb * N + i) * NCLASS + cl];
    zsum += pz[(size_t)jb * N + i];
  }
  float o = nsum / zsum;
  o = o > 0.f ? o : expf(o) - 1.f;  // ELU
  float mo = o;
#pragma unroll
  for (int mk = 1; mk < 16; mk <<= 1) mo = fmaxf(mo, __shfl_xor(mo, mk, 16));
  float sum = expf(o - mo);
#pragma unroll
  for (int mk = 1; mk < 16; mk <<= 1) sum += __shfl_xor(sum, mk, 16);
  out[(size_t)i * NCLASS + cl] = o - mo - logf(sum);
}

// ---------------------------------------------------------------------------
extern "C" void kernel_launch(void* const* d_in, const int* in_sizes, int n_in,
                              void* d_out, int out_size, void* d_ws, size_t ws_size,
                              hipStream_t stream) {
  const float* x  = (const float*)d_in[0];
  const float* Wh = (const float*)d_in[1];
  const float* ah = (const float*)d_in[2];
  const float* Wo = (const float*)d_in[3];
  const float* ao = (const float*)d_in[4];
  float* out = (float*)d_out;

  char* base = (char*)d_ws;
  size_t off = 0;
  auto alloc_f = [&](size_t n) -> float* {
    float* p = (float*)(base + off);
    off = (off + n * sizeof(float) + 255) & ~(size_t)255;
    return p;
  };
  auto alloc_i = [&](size_t n) -> int* {
    int* p = (int*)(base + off);
    off = (off + n * sizeof(int) + 255) & ~(size_t)255;
    return p;
  };
  auto alloc_u16 = [&](size_t n) -> unsigned short* {
    unsigned short* p = (unsigned short*)(base + off);
    off = (off + n * sizeof(unsigned short) + 255) & ~(size_t)255;
    return p;
  };

  unsigned short* xbf = alloc_u16((size_t)N * NFEAT);
  unsigned short* Wt  = alloc_u16((size_t)NHEADS * NHID * NFEAT);
  unsigned short* Wt2 = alloc_u16((size_t)NCLASS * NFEAT);
  unsigned short* h1b = alloc_u16((size_t)NHEADS * N * NHID);
  float* ssrc1 = alloc_f((size_t)NHEADS * N);
  float* sdst1 = alloc_f((size_t)NHEADS * N);
  float* ts1   = alloc_f((size_t)NHEADS * N);
  int*   perm1 = alloc_i((size_t)NHEADS * N);
  int*   ksp1  = alloc_i((size_t)NHEADS * N);
  float* csA1  = alloc_f((size_t)NHEADS * NC * NHID);
  float* csB1  = alloc_f((size_t)NHEADS * NC * NHID);
  float* csAz1 = alloc_f(NHEADS * NC);
  float* csBz1 = alloc_f(NHEADS * NC);
  unsigned short* xcb = alloc_u16((size_t)N * NHEADS * NHID);
  float* h2    = alloc_f((size_t)N * NCLASS);
  float* ssrc2 = alloc_f(N);
  float* sdst2 = alloc_f(N);
  unsigned* tmax2u = (unsigned*)alloc_i(1);
  float* pnum  = alloc_f((size_t)JSPL * N * NCLASS);
  float* pz    = alloc_f((size_t)JSPL * N);

  if (off > ws_size) return;

  hipLaunchKernelGGL(k_pack, dim3(2113), dim3(256), 0, stream, x, Wh, Wo, xbf, Wt, Wt2, tmax2u);

  // ---- Layer 1 ----
  hipLaunchKernelGGL(k_gemm_h, dim3(N / 128, NHEADS), dim3(256), 0, stream, xbf, Wt, ah, h1b, ssrc1, sdst1);
  hipLaunchKernelGGL(k_rank, dim3(64, NHEADS), dim3(256), 0, stream, sdst1, ssrc1, ts1, perm1, ksp1);
  hipLaunchKernelGGL(k_chunksum1, dim3(64, NHEADS), dim3(256), 0, stream, ts1, perm1, h1b, csA1, csB1, csAz1, csBz1);
  hipLaunchKernelGGL(k_chunkscan1, dim3(NHEADS), dim3(1024), 0, stream, csA1, csB1, csAz1, csBz1);
  hipLaunchKernelGGL(k_combine1, dim3(NHEADS * 256), dim3(256), 0, stream, ssrc1, ts1, perm1, ksp1, h1b, csA1, csB1, csAz1, csBz1, xcb);

  // ---- Layer 2 (direct attention, j-split partials, R=4) ----
  hipLaunchKernelGGL(k_gemm2, dim3(N / 64), dim3(256), 0, stream, xcb, Wt2, ao, h2, ssrc2, sdst2, tmax2u);
  hipLaunchKernelGGL(k_attn2p, dim3(N / 8, JSPL), dim3(128), 0, stream, ssrc2, sdst2, h2, tmax2u, pnum, pz);
  hipLaunchKernelGGL(k_attn2f, dim3(N / 16), dim3(256), 0, stream, pnum, pz, out);
}

// Round 14
// 127.564 us; speedup vs baseline: 1.5917x; 1.0456x over previous
//
#include <hip/hip_runtime.h>
#include <math.h>

#define N 4096
#define NFEAT 512
#define NHID 64
#define NCLASS 16
#define NHEADS 8
#define ALPHA 0.2f
#define NC 256   // chunks per head (16 rows each)
#define JSPL 4   // layer-2 j-split
#define JLEN (N / JSPL)

typedef __attribute__((ext_vector_type(8))) short bf16x8;
typedef __attribute__((ext_vector_type(4))) float f32x4;

__device__ inline unsigned short f2bf(float f) {
  unsigned u = __float_as_uint(f);
  unsigned r = u + 0x7fffu + ((u >> 16) & 1u);  // RNE
  return (unsigned short)(r >> 16);
}
__device__ inline float bf2f(unsigned short u) {
  return __uint_as_float(((unsigned)u) << 16);
}
__device__ inline unsigned mono(float f) {
  unsigned u = __float_as_uint(f);
  return (u & 0x80000000u) ? ~u : (u | 0x80000000u);
}
__device__ inline float unmono(unsigned m) {
  return (m >> 31) ? __uint_as_float(m & 0x7FFFFFFFu) : __uint_as_float(~m);
}

// ---------------------------------------------------------------------------
// P0: pack. blocks [0,2048): x->bf16; [2048,2112): Wt=bf16(Wh^T);
// 2112: Wt2 + tmax2 init.
// ---------------------------------------------------------------------------
__global__ __launch_bounds__(256) void k_pack(const float* __restrict__ x,
                                              const float* __restrict__ Wh,
                                              const float* __restrict__ Wo,
                                              unsigned short* __restrict__ xb,
                                              unsigned short* __restrict__ Wt,
                                              unsigned short* __restrict__ Wt2,
                                              unsigned* __restrict__ tmax2u) {
  int b = blockIdx.x;
  if (b < 2048) {
    int i = (b * 256 + threadIdx.x) * 4;
    float4 v = *(const float4*)(x + i);
    ushort4 o;
    o.x = f2bf(v.x); o.y = f2bf(v.y); o.z = f2bf(v.z); o.w = f2bf(v.w);
    *(ushort4*)(xb + i) = o;
  } else if (b < 2112) {
    int idx = b - 2048;
    int kt = idx & 7, hd = idx >> 3;
    __shared__ float ld[64][65];
    const float* src = Wh + ((size_t)hd * NFEAT + kt * 64) * NHID;
    int r = threadIdx.x >> 2, c0 = (threadIdx.x & 3) * 16;
#pragma unroll
    for (int j = 0; j < 4; ++j) {
      float4 v = *(const float4*)(src + (size_t)r * NHID + c0 + j * 4);
      ld[r][c0 + j * 4 + 0] = v.x; ld[r][c0 + j * 4 + 1] = v.y;
      ld[r][c0 + j * 4 + 2] = v.z; ld[r][c0 + j * 4 + 3] = v.w;
    }
    __syncthreads();
    int n = threadIdx.x >> 2, kq = threadIdx.x & 3;
    unsigned short tmp[16];
#pragma unroll
    for (int j = 0; j < 16; ++j) tmp[j] = f2bf(ld[kq * 16 + j][n]);
    unsigned short* dst = Wt + ((size_t)hd * 64 + n) * NFEAT + kt * 64 + kq * 16;
    ((uint4*)dst)[0] = *(uint4*)tmp;
    ((uint4*)dst)[1] = *(uint4*)(tmp + 8);
  } else {
    for (int e = threadIdx.x; e < NFEAT * NCLASS; e += 256) {
      int n = e & 15, k = e >> 4;
      Wt2[(size_t)n * NFEAT + k] = f2bf(Wo[(size_t)k * NCLASS + n]);
    }
    if (threadIdx.x == 0) *tmax2u = 0u;  // mono(-inf)
  }
}

// ---------------------------------------------------------------------------
// K1: MFMA bf16 GEMM h = x @ Wh per head, 128x64 tile, 4 waves, fused scores.
// h stored bf16.
// ---------------------------------------------------------------------------
__global__ __launch_bounds__(256) void k_gemm_h(const unsigned short* __restrict__ xb,
                                                const unsigned short* __restrict__ Wt,
                                                const float* __restrict__ ah,
                                                unsigned short* __restrict__ h1b,
                                                float* __restrict__ ssrc,
                                                float* __restrict__ sdst) {
  const int hd = blockIdx.y;
  const int i0 = blockIdx.x * 128;
  const int t = threadIdx.x;
  const int w = t >> 6, lane = t & 63;
  const int lr = lane & 15, kg = lane >> 4;
  const int wm = (w & 1) * 64, wn = (w >> 1) * 32;
  __shared__ uint4 Als[128][4];
  __shared__ uint4 Bls[64][4];
  __shared__ float sredS[128][2];
  __shared__ float sredD[128][2];
  const unsigned short* xrow = xb + (size_t)i0 * NFEAT;
  const unsigned short* wrow = Wt + (size_t)hd * 64 * NFEAT;

  f32x4 acc[4][2];
#pragma unroll
  for (int a = 0; a < 4; ++a)
#pragma unroll
    for (int b = 0; b < 2; ++b) acc[a][b] = (f32x4){0.f, 0.f, 0.f, 0.f};

  const int ra = t >> 1, ua = (t & 1) * 2;
  const int rb = t >> 2, ub = t & 3;
  for (int k0 = 0; k0 < NFEAT; k0 += 32) {
    uint4 qa0 = *(const uint4*)(xrow + (size_t)ra * NFEAT + k0 + ua * 8);
    uint4 qa1 = *(const uint4*)(xrow + (size_t)ra * NFEAT + k0 + ua * 8 + 8);
    uint4 qb  = *(const uint4*)(wrow + (size_t)rb * NFEAT + k0 + ub * 8);
    Als[ra][(ua) ^ (ra & 3)] = qa0;
    Als[ra][(ua + 1) ^ (ra & 3)] = qa1;
    Bls[rb][ub ^ (rb & 3)] = qb;
    __syncthreads();
    bf16x8 af[4], bfv[2];
#pragma unroll
    for (int mb = 0; mb < 4; ++mb) {
      int row = wm + mb * 16 + lr;
      af[mb] = __builtin_bit_cast(bf16x8, Als[row][kg ^ (row & 3)]);
    }
#pragma unroll
    for (int nb = 0; nb < 2; ++nb) {
      int col = wn + nb * 16 + lr;
      bfv[nb] = __builtin_bit_cast(bf16x8, Bls[col][kg ^ (col & 3)]);
    }
#pragma unroll
    for (int mb = 0; mb < 4; ++mb)
#pragma unroll
      for (int nb = 0; nb < 2; ++nb)
        acc[mb][nb] = __builtin_amdgcn_mfma_f32_16x16x32_bf16(af[mb], bfv[nb], acc[mb][nb], 0, 0, 0);
    __syncthreads();
  }

  unsigned short* hout = h1b + ((size_t)hd * N + i0) * NHID;
#pragma unroll
  for (int mb = 0; mb < 4; ++mb)
#pragma unroll
    for (int nb = 0; nb < 2; ++nb) {
      int rbase = wm + mb * 16 + kg * 4;
      int col = wn + nb * 16 + lr;
#pragma unroll
      for (int reg = 0; reg < 4; ++reg)
        hout[(size_t)(rbase + reg) * NHID + col] = f2bf(acc[mb][nb][reg]);
    }

  float aS[2], aD[2];
#pragma unroll
  for (int nb = 0; nb < 2; ++nb) {
    aS[nb] = ah[hd * 128 + wn + nb * 16 + lr];
    aD[nb] = ah[hd * 128 + 64 + wn + nb * 16 + lr];
  }
#pragma unroll
  for (int mb = 0; mb < 4; ++mb)
#pragma unroll
    for (int reg = 0; reg < 4; ++reg) {
      float ps = acc[mb][0][reg] * aS[0] + acc[mb][1][reg] * aS[1];
      float pd = acc[mb][0][reg] * aD[0] + acc[mb][1][reg] * aD[1];
#pragma unroll
      for (int m = 1; m < 16; m <<= 1) { ps += __shfl_xor(ps, m); pd += __shfl_xor(pd, m); }
      if (lr == 0) {
        int rl = wm + mb * 16 + kg * 4 + reg;
        sredS[rl][w >> 1] = ps;
        sredD[rl][w >> 1] = pd;
      }
    }
  __syncthreads();
  if (t < 128) {
    ssrc[(size_t)hd * N + i0 + t] = sredS[t][0] + sredS[t][1];
    sdst[(size_t)hd * N + i0 + t] = sredD[t][0] + sredD[t][1];
  }
}

// ---------------------------------------------------------------------------
// K4: ballot rank + per-row split-k (layer 1 only). u32 keys.
// ---------------------------------------------------------------------------
__global__ __launch_bounds__(256) void k_rank(const float* __restrict__ t,
                                              const float* __restrict__ ssrc,
                                              float* __restrict__ ts,
                                              int* __restrict__ perm,
                                              int* __restrict__ ksp) {
  int hd = blockIdx.y;
  const float* th = t + (size_t)hd * N;
  __shared__ unsigned skey[N];
  int tid = threadIdx.x;
  for (int i = tid; i < N; i += 256)
    skey[i] = (mono(th[i]) & 0xFFFFF000u) | (unsigned)i;
  __syncthreads();
  int wv = tid >> 6, lane = tid & 63;
  int jbase = blockIdx.x * 64 + wv * 16;
  unsigned kj[16], qk[16];
  int cnt[16], cq[16];
#pragma unroll
  for (int jj = 0; jj < 16; ++jj) {
    kj[jj] = skey[jbase + jj];
    qk[jj] = (mono(-ssrc[(size_t)hd * N + jbase + jj]) & 0xFFFFF000u) | 0xFFFu;
    cnt[jj] = 0; cq[jj] = 0;
  }
  for (int c = 0; c < N; c += 64) {
    unsigned key = skey[c + lane];
#pragma unroll
    for (int jj = 0; jj < 16; ++jj) {
      cnt[jj] += __popcll(__ballot(key < kj[jj]));
      cq[jj]  += __popcll(__ballot(key < qk[jj]));
    }
  }
  int myc = 0, myq = 0;
#pragma unroll
  for (int jj = 0; jj < 16; ++jj)
    if (lane == jj) { myc = cnt[jj]; myq = cq[jj]; }
  if (lane < 16) {
    int j = jbase + lane;
    ts[(size_t)hd * N + myc] = th[j];
    perm[(size_t)hd * N + myc] = j;
    ksp[(size_t)hd * N + j] = myq;
  }
}

// ---------------------------------------------------------------------------
// K5a: chunksum layer 1 (wide grid for the gather). One wave per 16-row
// chunk; grid (64, 8) x 256 thr = 2048 waves.
// ---------------------------------------------------------------------------
__global__ __launch_bounds__(256) void k_chunksum1(const float* __restrict__ ts,
                                                   const int* __restrict__ perm,
                                                   const unsigned short* __restrict__ h1b,
                                                   float* __restrict__ csA,
                                                   float* __restrict__ csB,
                                                   float* __restrict__ csAz,
                                                   float* __restrict__ csBz) {
  int hd = blockIdx.y, lane = threadIdx.x & 63;
  int c = blockIdx.x * 4 + (threadIdx.x >> 6);
  int r0 = c * 16;
  float tm = ts[(size_t)hd * N + N - 1];
  float tvv = ts[(size_t)hd * N + r0 + (lane & 15)];
  float ev = expf((lane < 16 ? ALPHA : 1.f) * (tvv - tm));
  int pvv = perm[(size_t)hd * N + r0 + (lane & 15)];
  float sA = 0.f, sB = 0.f, zA = 0.f, zB = 0.f;
#pragma unroll
  for (int r = 0; r < 16; ++r) {
    float eA = __shfl(ev, r);
    float eB = __shfl(ev, 16 + r);
    int p = __shfl(pvv, r);
    float hv = bf2f(h1b[((size_t)hd * N + p) * NHID + lane]);
    sA += eA * hv; sB += eB * hv; zA += eA; zB += eB;
  }
  csA[((size_t)hd * NC + c) * NHID + lane] = sA;
  csB[((size_t)hd * NC + c) * NHID + lane] = sB;
  if (lane == 0) { csAz[hd * NC + c] = zA; csBz[hd * NC + c] = zB; }
}

// ---------------------------------------------------------------------------
// K5b: scan-only layer 1 (narrow; no gather). 8 blocks x 1024 thr.
// ---------------------------------------------------------------------------
__global__ __launch_bounds__(1024) void k_chunkscan1(float* __restrict__ csA,
                                                     float* __restrict__ csB,
                                                     float* __restrict__ csAz,
                                                     float* __restrict__ csBz) {
  int hd = blockIdx.x;
  int t = threadIdx.x, w = t >> 6, lane = t & 63;
  __shared__ float pA[16][64], pB[16][64];
  __shared__ float pAz[16], pBz[16];
  float rA[16], rB[16], rAz[16], rBz[16];
#pragma unroll
  for (int cc = 0; cc < 16; ++cc) {
    int c = w * 16 + cc;
    rA[cc] = csA[((size_t)hd * NC + c) * NHID + lane];
    rB[cc] = csB[((size_t)hd * NC + c) * NHID + lane];
    rAz[cc] = csAz[hd * NC + c];
    rBz[cc] = csBz[hd * NC + c];
  }
  float tA = 0.f, tB = 0.f, tAz = 0.f, tBz = 0.f;
#pragma unroll
  for (int cc = 0; cc < 16; ++cc) { tA += rA[cc]; tB += rB[cc]; tAz += rAz[cc]; tBz += rBz[cc]; }
  pA[w][lane] = tA; pB[w][lane] = tB;
  if (lane == 0) { pAz[w] = tAz; pBz[w] = tBz; }
  __syncthreads();
  float bA = 0.f, bAz = 0.f, bB = 0.f, bBz = 0.f;
  for (int w2 = 0; w2 < w; ++w2) { bA += pA[w2][lane]; bAz += pAz[w2]; }
  for (int w2 = w + 1; w2 < 16; ++w2) { bB += pB[w2][lane]; bBz += pBz[w2]; }
  float run = bA, runz = bAz;
#pragma unroll
  for (int cc = 0; cc < 16; ++cc) {
    int c = w * 16 + cc;
    csA[((size_t)hd * NC + c) * NHID + lane] = run; run += rA[cc];
    if (lane == 0) csAz[hd * NC + c] = runz;
    runz += rAz[cc];
  }
  run = bB; runz = bBz;
#pragma unroll
  for (int cc = 15; cc >= 0; --cc) {
    int c = w * 16 + cc;
    csB[((size_t)hd * NC + c) * NHID + lane] = run; run += rB[cc];
    if (lane == 0) csBz[hd * NC + c] = runz;
    runz += rBz[cc];
  }
}

// ---------------------------------------------------------------------------
// K6: layer-1 combine. Precomputed split-k; chunk bases + 16-term rebuild.
// ---------------------------------------------------------------------------
__global__ __launch_bounds__(256) void k_combine1(const float* __restrict__ ssrc,
                                                  const float* __restrict__ ts,
                                                  const int* __restrict__ perm,
                                                  const int* __restrict__ ksp,
                                                  const unsigned short* __restrict__ h1b,
                                                  const float* __restrict__ csA,
                                                  const float* __restrict__ csB,
                                                  const float* __restrict__ csAz,
                                                  const float* __restrict__ csBz,
                                                  unsigned short* __restrict__ xcb) {
  int hd = blockIdx.x >> 8;
  int base = (blockIdx.x & 255) * 16;
  int w = threadIdx.x >> 6, lane = threadIdx.x & 63;
  const float* tsh = ts + (size_t)hd * N;
  float tm = tsh[N - 1];
  for (int it = 0; it < 4; ++it) {
    int i = base + w * 4 + it;
    float s = ssrc[(size_t)hd * N + i];
    int k = ksp[(size_t)hd * N + i];
    int c = k >> 4; if (c > NC - 1) c = NC - 1;
    int c0 = c * 16;
    float v = s + tm;
    float m = fmaxf(v, ALPHA * v);
    float wA = expf(ALPHA * v - m), wB = expf(v - m);
    size_t cb = (size_t)hd * NC + c;
    float numA = csA[cb * NHID + lane];
    float numB = csB[cb * NHID + lane];
    float zA = csAz[cb], zB = csBz[cb];
    int r15 = lane & 15;
    float tvv = tsh[c0 + r15];
    int pvv = perm[(size_t)hd * N + c0 + r15];
    float ev = expf(((c0 + r15) < k ? ALPHA : 1.f) * (tvv - tm));
#pragma unroll
    for (int r = 0; r < 16; ++r) {
      float e = __shfl(ev, r);
      int p = __shfl(pvv, r);
      float hv = bf2f(h1b[((size_t)hd * N + p) * NHID + lane]);
      bool isA = (c0 + r) < k;
      if (isA) { numA += e * hv; zA += e; } else { numB += e * hv; zB += e; }
    }
    float Z = wA * zA + wB * zB;
    float f = (wA * numA + wB * numB) / Z;
    float e2 = f > 0.f ? f : expf(f) - 1.f;
    xcb[(size_t)i * (NHEADS * NHID) + hd * NHID + lane] = f2bf(e2);
  }
}

// ---------------------------------------------------------------------------
// K7: h2 = xc @ Wo via MFMA + fused layer-2 scores + deterministic global
// tmax. h2 now stored bf16 (feeds the LDS-staged attention).
// ---------------------------------------------------------------------------
__global__ __launch_bounds__(256) void k_gemm2(const unsigned short* __restrict__ xcb,
                                               const unsigned short* __restrict__ Wt2,
                                               const float* __restrict__ ao,
                                               unsigned short* __restrict__ h2b,
                                               float* __restrict__ ssrc,
                                               float* __restrict__ sdst,
                                               unsigned* __restrict__ tmax2u) {
  const int t = threadIdx.x;
  const int w = t >> 6, lane = t & 63;
  const int lr = lane & 15, kg = lane >> 4;
  const int i0 = blockIdx.x * 64 + w * 16;
  __shared__ float sd[64];
  f32x4 acc = (f32x4){0.f, 0.f, 0.f, 0.f};
  const unsigned short* arow = xcb + (size_t)(i0 + lr) * NFEAT;
  const unsigned short* brow = Wt2 + (size_t)lr * NFEAT;
#pragma unroll
  for (int k0 = 0; k0 < NFEAT; k0 += 32) {
    bf16x8 af = __builtin_bit_cast(bf16x8, *(const uint4*)(arow + k0 + kg * 8));
    bf16x8 bv = __builtin_bit_cast(bf16x8, *(const uint4*)(brow + k0 + kg * 8));
    acc = __builtin_amdgcn_mfma_f32_16x16x32_bf16(af, bv, acc, 0, 0, 0);
  }
  float aS = ao[lr], aD = ao[16 + lr];
#pragma unroll
  for (int reg = 0; reg < 4; ++reg) {
    int row = i0 + kg * 4 + reg;
    h2b[(size_t)row * NCLASS + lr] = f2bf(acc[reg]);
    float ps = acc[reg] * aS, pd = acc[reg] * aD;
#pragma unroll
    for (int m = 1; m < 16; m <<= 1) { ps += __shfl_xor(ps, m); pd += __shfl_xor(pd, m); }
    if (lr == 0) {
      ssrc[row] = ps;
      sdst[row] = pd;
      sd[w * 16 + kg * 4 + reg] = pd;
    }
  }
  __syncthreads();
  if (t < 64) {
    float v = sd[t];
#pragma unroll
    for (int m = 32; m; m >>= 1) v = fmaxf(v, __shfl_xor(v, m));
    if (t == 0) atomicMax(tmax2u, mono(v));
  }
}

// ---------------------------------------------------------------------------
// K8a: layer-2 attention partials, h2 slice staged in LDS as bf16 with
// 9-dword padded rows (gcd(9,32)=1 -> conflict-free ds_read_b32).
// grid (256 row-blocks, JSPL=4) x 256 thr (4 waves, R=4 rows/wave).
// ---------------------------------------------------------------------------
__global__ __launch_bounds__(256) void k_attn2p(const float* __restrict__ ssrc,
                                                const float* __restrict__ t,
                                                const unsigned short* __restrict__ h2b,
                                                const unsigned* __restrict__ tmax2u,
                                                float* __restrict__ pnum,
                                                float* __restrict__ pz) {
  __shared__ float tl[JLEN];          // 4 KB
  __shared__ unsigned hs[JLEN * 9];   // 36 KB: 8 packed-bf16 dwords + 1 pad/row
  int tid = threadIdx.x;
  int jb = blockIdx.y;
  {
    int i4 = tid * 4;
    *(float4*)(tl + i4) = *(const float4*)(t + jb * JLEN + i4);
  }
#pragma unroll
  for (int rep = 0; rep < 4; ++rep) {
    int j = rep * 256 + tid;
    const uint4* src = (const uint4*)(h2b + (size_t)(jb * JLEN + j) * NCLASS);
    uint4 a = src[0], b = src[1];
    unsigned* dst = hs + j * 9;
    dst[0] = a.x; dst[1] = a.y; dst[2] = a.z; dst[3] = a.w;
    dst[4] = b.x; dst[5] = b.y; dst[6] = b.z; dst[7] = b.w;
  }
  __syncthreads();
  int w = tid >> 6, lane = tid & 63;
  int ib = blockIdx.x * 16 + w * 4;
  float tmax = unmono(*tmax2u);
  float s[4], rowm[4], Z[4];
  float num[4][16];
#pragma unroll
  for (int r = 0; r < 4; ++r) {
    s[r] = ssrc[ib + r];
    float v = s[r] + tmax;
    rowm[r] = fmaxf(v, ALPHA * v);  // exact global row max (monotone LR)
    Z[r] = 0.f;
#pragma unroll
    for (int c = 0; c < 16; ++c) num[r][c] = 0.f;
  }
  for (int jj = lane; jj < JLEN; jj += 64) {
    float tj = tl[jj];
    float e[4];
#pragma unroll
    for (int r = 0; r < 4; ++r) {
      float v = s[r] + tj;
      e[r] = expf(fmaxf(v, ALPHA * v) - rowm[r]);
      Z[r] += e[r];
    }
    const unsigned* hrow = hs + jj * 9;
#pragma unroll
    for (int c2 = 0; c2 < 8; ++c2) {
      unsigned u = hrow[c2];
      float flo = __uint_as_float(u << 16);          // even class
      float fhi = __uint_as_float(u & 0xFFFF0000u);  // odd class
#pragma unroll
      for (int r = 0; r < 4; ++r) {
        num[r][2 * c2]     += e[r] * flo;
        num[r][2 * c2 + 1] += e[r] * fhi;
      }
    }
  }
#pragma unroll
  for (int m = 32; m; m >>= 1) {
#pragma unroll
    for (int r = 0; r < 4; ++r) {
      Z[r] += __shfl_xor(Z[r], m);
#pragma unroll
      for (int c = 0; c < 16; ++c) num[r][c] += __shfl_xor(num[r][c], m);
    }
  }
#pragma unroll
  for (int r = 0; r < 4; ++r) {
    float ov = 0.f;
#pragma unroll
    for (int c = 0; c < 16; ++c) if (lane == c) ov = num[r][c];  // static select
    if (lane < 16) pnum[((size_t)jb * N + ib + r) * NCLASS + lane] = ov;
    if (lane == 16) pz[(size_t)jb * N + ib + r] = Z[r];
  }
}

// ---------------------------------------------------------------------------
// K8b: combine partials + ELU + log_softmax. 256 blocks x 256 thr
// (16 rows/block, 16 lanes/row).
// ---------------------------------------------------------------------------
__global__ __launch_bounds__(256) void k_attn2f(const float* __restrict__ pnum,
                                                const float* __restrict__ pz,
                                                float* __restrict__ out) {
  int g = threadIdx.x >> 4, cl = threadIdx.x & 15;
  int i = blockIdx.x * 16 + g;
  float nsum = 0.f, zsum = 0.f;
#pragma unroll
  for (int jb = 0; jb < JSPL; ++jb) {
    nsum += pnum[((size_t)jb * N + i) * NCLASS + cl];
    zsum += pz[(size_t)jb * N + i];
  }
  float o = nsum / zsum;
  o = o > 0.f ? o : expf(o) - 1.f;  // ELU
  float mo = o;
#pragma unroll
  for (int mk = 1; mk < 16; mk <<= 1) mo = fmaxf(mo, __shfl_xor(mo, mk, 16));
  float sum = expf(o - mo);
#pragma unroll
  for (int mk = 1; mk < 16; mk <<= 1) sum += __shfl_xor(sum, mk, 16);
  out[(size_t)i * NCLASS + cl] = o - mo - logf(sum);
}

// ---------------------------------------------------------------------------
extern "C" void kernel_launch(void* const* d_in, const int* in_sizes, int n_in,
                              void* d_out, int out_size, void* d_ws, size_t ws_size,
                              hipStream_t stream) {
  const float* x  = (const float*)d_in[0];
  const float* Wh = (const float*)d_in[1];
  const float* ah = (const float*)d_in[2];
  const float* Wo = (const float*)d_in[3];
  const float* ao = (const float*)d_in[4];
  float* out = (float*)d_out;

  char* base = (char*)d_ws;
  size_t off = 0;
  auto alloc_f = [&](size_t n) -> float* {
    float* p = (float*)(base + off);
    off = (off + n * sizeof(float) + 255) & ~(size_t)255;
    return p;
  };
  auto alloc_i = [&](size_t n) -> int* {
    int* p = (int*)(base + off);
    off = (off + n * sizeof(int) + 255) & ~(size_t)255;
    return p;
  };
  auto alloc_u16 = [&](size_t n) -> unsigned short* {
    unsigned short* p = (unsigned short*)(base + off);
    off = (off + n * sizeof(unsigned short) + 255) & ~(size_t)255;
    return p;
  };

  unsigned short* xbf = alloc_u16((size_t)N * NFEAT);
  unsigned short* Wt  = alloc_u16((size_t)NHEADS * NHID * NFEAT);
  unsigned short* Wt2 = alloc_u16((size_t)NCLASS * NFEAT);
  unsigned short* h1b = alloc_u16((size_t)NHEADS * N * NHID);
  float* ssrc1 = alloc_f((size_t)NHEADS * N);
  float* sdst1 = alloc_f((size_t)NHEADS * N);
  float* ts1   = alloc_f((size_t)NHEADS * N);
  int*   perm1 = alloc_i((size_t)NHEADS * N);
  int*   ksp1  = alloc_i((size_t)NHEADS * N);
  float* csA1  = alloc_f((size_t)NHEADS * NC * NHID);
  float* csB1  = alloc_f((size_t)NHEADS * NC * NHID);
  float* csAz1 = alloc_f(NHEADS * NC);
  float* csBz1 = alloc_f(NHEADS * NC);
  unsigned short* xcb = alloc_u16((size_t)N * NHEADS * NHID);
  unsigned short* h2b = alloc_u16((size_t)N * NCLASS);
  float* ssrc2 = alloc_f(N);
  float* sdst2 = alloc_f(N);
  unsigned* tmax2u = (unsigned*)alloc_i(1);
  float* pnum  = alloc_f((size_t)JSPL * N * NCLASS);
  float* pz    = alloc_f((size_t)JSPL * N);

  if (off > ws_size) return;

  hipLaunchKernelGGL(k_pack, dim3(2113), dim3(256), 0, stream, x, Wh, Wo, xbf, Wt, Wt2, tmax2u);

  // ---- Layer 1 ----
  hipLaunchKernelGGL(k_gemm_h, dim3(N / 128, NHEADS), dim3(256), 0, stream, xbf, Wt, ah, h1b, ssrc1, sdst1);
  hipLaunchKernelGGL(k_rank, dim3(64, NHEADS), dim3(256), 0, stream, sdst1, ssrc1, ts1, perm1, ksp1);
  hipLaunchKernelGGL(k_chunksum1, dim3(64, NHEADS), dim3(256), 0, stream, ts1, perm1, h1b, csA1, csB1, csAz1, csBz1);
  hipLaunchKernelGGL(k_chunkscan1, dim3(NHEADS), dim3(1024), 0, stream, csA1, csB1, csAz1, csBz1);
  hipLaunchKernelGGL(k_combine1, dim3(NHEADS * 256), dim3(256), 0, stream, ssrc1, ts1, perm1, ksp1, h1b, csA1, csB1, csAz1, csBz1, xcb);

  // ---- Layer 2 (direct attention, LDS-staged bf16 h2) ----
  hipLaunchKernelGGL(k_gemm2, dim3(N / 64), dim3(256), 0, stream, xcb, Wt2, ao, h2b, ssrc2, sdst2, tmax2u);
  hipLaunchKernelGGL(k_attn2p, dim3(N / 16, JSPL), dim3(256), 0, stream, ssrc2, sdst2, h2b, tmax2u, pnum, pz);
  hipLaunchKernelGGL(k_attn2f, dim3(N / 16), dim3(256), 0, stream, pnum, pz, out);
}

// Round 15
// 107.397 us; speedup vs baseline: 1.8906x; 1.1878x over previous
//
#include <hip/hip_runtime.h>
#include <math.h>

#define N 4096
#define NFEAT 512
#define NHID 64
#define NCLASS 16
#define NHEADS 8
#define ALPHA 0.2f
#define NC 256   // chunks per head (16 rows each)
#define JSPL 8   // layer-2 j-split
#define JLEN (N / JSPL)   // 512
#define HSTR 520          // padded hsT row stride (ushorts); 2-way banks = free

typedef __attribute__((ext_vector_type(8))) short bf16x8;
typedef __attribute__((ext_vector_type(4))) float f32x4;

__device__ inline unsigned short f2bf(float f) {
  unsigned u = __float_as_uint(f);
  unsigned r = u + 0x7fffu + ((u >> 16) & 1u);  // RNE
  return (unsigned short)(r >> 16);
}
__device__ inline float bf2f(unsigned short u) {
  return __uint_as_float(((unsigned)u) << 16);
}
__device__ inline unsigned mono(float f) {
  unsigned u = __float_as_uint(f);
  return (u & 0x80000000u) ? ~u : (u | 0x80000000u);
}
__device__ inline float unmono(unsigned m) {
  return (m >> 31) ? __uint_as_float(m & 0x7FFFFFFFu) : __uint_as_float(~m);
}

// ---------------------------------------------------------------------------
// P0: pack. blocks [0,2048): x->bf16; [2048,2112): Wt=bf16(Wh^T);
// 2112: Wt2 + tmax2 init.
// ---------------------------------------------------------------------------
__global__ __launch_bounds__(256) void k_pack(const float* __restrict__ x,
                                              const float* __restrict__ Wh,
                                              const float* __restrict__ Wo,
                                              unsigned short* __restrict__ xb,
                                              unsigned short* __restrict__ Wt,
                                              unsigned short* __restrict__ Wt2,
                                              unsigned* __restrict__ tmax2u) {
  int b = blockIdx.x;
  if (b < 2048) {
    int i = (b * 256 + threadIdx.x) * 4;
    float4 v = *(const float4*)(x + i);
    ushort4 o;
    o.x = f2bf(v.x); o.y = f2bf(v.y); o.z = f2bf(v.z); o.w = f2bf(v.w);
    *(ushort4*)(xb + i) = o;
  } else if (b < 2112) {
    int idx = b - 2048;
    int kt = idx & 7, hd = idx >> 3;
    __shared__ float ld[64][65];
    const float* src = Wh + ((size_t)hd * NFEAT + kt * 64) * NHID;
    int r = threadIdx.x >> 2, c0 = (threadIdx.x & 3) * 16;
#pragma unroll
    for (int j = 0; j < 4; ++j) {
      float4 v = *(const float4*)(src + (size_t)r * NHID + c0 + j * 4);
      ld[r][c0 + j * 4 + 0] = v.x; ld[r][c0 + j * 4 + 1] = v.y;
      ld[r][c0 + j * 4 + 2] = v.z; ld[r][c0 + j * 4 + 3] = v.w;
    }
    __syncthreads();
    int n = threadIdx.x >> 2, kq = threadIdx.x & 3;
    unsigned short tmp[16];
#pragma unroll
    for (int j = 0; j < 16; ++j) tmp[j] = f2bf(ld[kq * 16 + j][n]);
    unsigned short* dst = Wt + ((size_t)hd * 64 + n) * NFEAT + kt * 64 + kq * 16;
    ((uint4*)dst)[0] = *(uint4*)tmp;
    ((uint4*)dst)[1] = *(uint4*)(tmp + 8);
  } else {
    for (int e = threadIdx.x; e < NFEAT * NCLASS; e += 256) {
      int n = e & 15, k = e >> 4;
      Wt2[(size_t)n * NFEAT + k] = f2bf(Wo[(size_t)k * NCLASS + n]);
    }
    if (threadIdx.x == 0) *tmax2u = 0u;  // mono(-inf)
  }
}

// ---------------------------------------------------------------------------
// K1: MFMA bf16 GEMM h = x @ Wh per head, 128x64 tile, 4 waves, fused scores.
// h stored bf16.
// ---------------------------------------------------------------------------
__global__ __launch_bounds__(256) void k_gemm_h(const unsigned short* __restrict__ xb,
                                                const unsigned short* __restrict__ Wt,
                                                const float* __restrict__ ah,
                                                unsigned short* __restrict__ h1b,
                                                float* __restrict__ ssrc,
                                                float* __restrict__ sdst) {
  const int hd = blockIdx.y;
  const int i0 = blockIdx.x * 128;
  const int t = threadIdx.x;
  const int w = t >> 6, lane = t & 63;
  const int lr = lane & 15, kg = lane >> 4;
  const int wm = (w & 1) * 64, wn = (w >> 1) * 32;
  __shared__ uint4 Als[128][4];
  __shared__ uint4 Bls[64][4];
  __shared__ float sredS[128][2];
  __shared__ float sredD[128][2];
  const unsigned short* xrow = xb + (size_t)i0 * NFEAT;
  const unsigned short* wrow = Wt + (size_t)hd * 64 * NFEAT;

  f32x4 acc[4][2];
#pragma unroll
  for (int a = 0; a < 4; ++a)
#pragma unroll
    for (int b = 0; b < 2; ++b) acc[a][b] = (f32x4){0.f, 0.f, 0.f, 0.f};

  const int ra = t >> 1, ua = (t & 1) * 2;
  const int rb = t >> 2, ub = t & 3;
  for (int k0 = 0; k0 < NFEAT; k0 += 32) {
    uint4 qa0 = *(const uint4*)(xrow + (size_t)ra * NFEAT + k0 + ua * 8);
    uint4 qa1 = *(const uint4*)(xrow + (size_t)ra * NFEAT + k0 + ua * 8 + 8);
    uint4 qb  = *(const uint4*)(wrow + (size_t)rb * NFEAT + k0 + ub * 8);
    Als[ra][(ua) ^ (ra & 3)] = qa0;
    Als[ra][(ua + 1) ^ (ra & 3)] = qa1;
    Bls[rb][ub ^ (rb & 3)] = qb;
    __syncthreads();
    bf16x8 af[4], bfv[2];
#pragma unroll
    for (int mb = 0; mb < 4; ++mb) {
      int row = wm + mb * 16 + lr;
      af[mb] = __builtin_bit_cast(bf16x8, Als[row][kg ^ (row & 3)]);
    }
#pragma unroll
    for (int nb = 0; nb < 2; ++nb) {
      int col = wn + nb * 16 + lr;
      bfv[nb] = __builtin_bit_cast(bf16x8, Bls[col][kg ^ (col & 3)]);
    }
#pragma unroll
    for (int mb = 0; mb < 4; ++mb)
#pragma unroll
      for (int nb = 0; nb < 2; ++nb)
        acc[mb][nb] = __builtin_amdgcn_mfma_f32_16x16x32_bf16(af[mb], bfv[nb], acc[mb][nb], 0, 0, 0);
    __syncthreads();
  }

  unsigned short* hout = h1b + ((size_t)hd * N + i0) * NHID;
#pragma unroll
  for (int mb = 0; mb < 4; ++mb)
#pragma unroll
    for (int nb = 0; nb < 2; ++nb) {
      int rbase = wm + mb * 16 + kg * 4;
      int col = wn + nb * 16 + lr;
#pragma unroll
      for (int reg = 0; reg < 4; ++reg)
        hout[(size_t)(rbase + reg) * NHID + col] = f2bf(acc[mb][nb][reg]);
    }

  float aS[2], aD[2];
#pragma unroll
  for (int nb = 0; nb < 2; ++nb) {
    aS[nb] = ah[hd * 128 + wn + nb * 16 + lr];
    aD[nb] = ah[hd * 128 + 64 + wn + nb * 16 + lr];
  }
#pragma unroll
  for (int mb = 0; mb < 4; ++mb)
#pragma unroll
    for (int reg = 0; reg < 4; ++reg) {
      float ps = acc[mb][0][reg] * aS[0] + acc[mb][1][reg] * aS[1];
      float pd = acc[mb][0][reg] * aD[0] + acc[mb][1][reg] * aD[1];
#pragma unroll
      for (int m = 1; m < 16; m <<= 1) { ps += __shfl_xor(ps, m); pd += __shfl_xor(pd, m); }
      if (lr == 0) {
        int rl = wm + mb * 16 + kg * 4 + reg;
        sredS[rl][w >> 1] = ps;
        sredD[rl][w >> 1] = pd;
      }
    }
  __syncthreads();
  if (t < 128) {
    ssrc[(size_t)hd * N + i0 + t] = sredS[t][0] + sredS[t][1];
    sdst[(size_t)hd * N + i0 + t] = sredD[t][0] + sredD[t][1];
  }
}

// ---------------------------------------------------------------------------
// K4: ballot rank + per-row split-k (layer 1 only). u32 keys.
// ---------------------------------------------------------------------------
__global__ __launch_bounds__(256) void k_rank(const float* __restrict__ t,
                                              const float* __restrict__ ssrc,
                                              float* __restrict__ ts,
                                              int* __restrict__ perm,
                                              int* __restrict__ ksp) {
  int hd = blockIdx.y;
  const float* th = t + (size_t)hd * N;
  __shared__ unsigned skey[N];
  int tid = threadIdx.x;
  for (int i = tid; i < N; i += 256)
    skey[i] = (mono(th[i]) & 0xFFFFF000u) | (unsigned)i;
  __syncthreads();
  int wv = tid >> 6, lane = tid & 63;
  int jbase = blockIdx.x * 64 + wv * 16;
  unsigned kj[16], qk[16];
  int cnt[16], cq[16];
#pragma unroll
  for (int jj = 0; jj < 16; ++jj) {
    kj[jj] = skey[jbase + jj];
    qk[jj] = (mono(-ssrc[(size_t)hd * N + jbase + jj]) & 0xFFFFF000u) | 0xFFFu;
    cnt[jj] = 0; cq[jj] = 0;
  }
  for (int c = 0; c < N; c += 64) {
    unsigned key = skey[c + lane];
#pragma unroll
    for (int jj = 0; jj < 16; ++jj) {
      cnt[jj] += __popcll(__ballot(key < kj[jj]));
      cq[jj]  += __popcll(__ballot(key < qk[jj]));
    }
  }
  int myc = 0, myq = 0;
#pragma unroll
  for (int jj = 0; jj < 16; ++jj)
    if (lane == jj) { myc = cnt[jj]; myq = cq[jj]; }
  if (lane < 16) {
    int j = jbase + lane;
    ts[(size_t)hd * N + myc] = th[j];
    perm[(size_t)hd * N + myc] = j;
    ksp[(size_t)hd * N + j] = myq;
  }
}

// ---------------------------------------------------------------------------
// K5a: chunksum layer 1 (wide grid for the gather). One wave per 16-row
// chunk; grid (64, 8) x 256 thr = 2048 waves.
// ---------------------------------------------------------------------------
__global__ __launch_bounds__(256) void k_chunksum1(const float* __restrict__ ts,
                                                   const int* __restrict__ perm,
                                                   const unsigned short* __restrict__ h1b,
                                                   float* __restrict__ csA,
                                                   float* __restrict__ csB,
                                                   float* __restrict__ csAz,
                                                   float* __restrict__ csBz) {
  int hd = blockIdx.y, lane = threadIdx.x & 63;
  int c = blockIdx.x * 4 + (threadIdx.x >> 6);
  int r0 = c * 16;
  float tm = ts[(size_t)hd * N + N - 1];
  float tvv = ts[(size_t)hd * N + r0 + (lane & 15)];
  float ev = expf((lane < 16 ? ALPHA : 1.f) * (tvv - tm));
  int pvv = perm[(size_t)hd * N + r0 + (lane & 15)];
  float sA = 0.f, sB = 0.f, zA = 0.f, zB = 0.f;
#pragma unroll
  for (int r = 0; r < 16; ++r) {
    float eA = __shfl(ev, r);
    float eB = __shfl(ev, 16 + r);
    int p = __shfl(pvv, r);
    float hv = bf2f(h1b[((size_t)hd * N + p) * NHID + lane]);
    sA += eA * hv; sB += eB * hv; zA += eA; zB += eB;
  }
  csA[((size_t)hd * NC + c) * NHID + lane] = sA;
  csB[((size_t)hd * NC + c) * NHID + lane] = sB;
  if (lane == 0) { csAz[hd * NC + c] = zA; csBz[hd * NC + c] = zB; }
}

// ---------------------------------------------------------------------------
// K5b: scan-only layer 1 (narrow; no gather). 8 blocks x 1024 thr.
// ---------------------------------------------------------------------------
__global__ __launch_bounds__(1024) void k_chunkscan1(float* __restrict__ csA,
                                                     float* __restrict__ csB,
                                                     float* __restrict__ csAz,
                                                     float* __restrict__ csBz) {
  int hd = blockIdx.x;
  int t = threadIdx.x, w = t >> 6, lane = t & 63;
  __shared__ float pA[16][64], pB[16][64];
  __shared__ float pAz[16], pBz[16];
  float rA[16], rB[16], rAz[16], rBz[16];
#pragma unroll
  for (int cc = 0; cc < 16; ++cc) {
    int c = w * 16 + cc;
    rA[cc] = csA[((size_t)hd * NC + c) * NHID + lane];
    rB[cc] = csB[((size_t)hd * NC + c) * NHID + lane];
    rAz[cc] = csAz[hd * NC + c];
    rBz[cc] = csBz[hd * NC + c];
  }
  float tA = 0.f, tB = 0.f, tAz = 0.f, tBz = 0.f;
#pragma unroll
  for (int cc = 0; cc < 16; ++cc) { tA += rA[cc]; tB += rB[cc]; tAz += rAz[cc]; tBz += rBz[cc]; }
  pA[w][lane] = tA; pB[w][lane] = tB;
  if (lane == 0) { pAz[w] = tAz; pBz[w] = tBz; }
  __syncthreads();
  float bA = 0.f, bAz = 0.f, bB = 0.f, bBz = 0.f;
  for (int w2 = 0; w2 < w; ++w2) { bA += pA[w2][lane]; bAz += pAz[w2]; }
  for (int w2 = w + 1; w2 < 16; ++w2) { bB += pB[w2][lane]; bBz += pBz[w2]; }
  float run = bA, runz = bAz;
#pragma unroll
  for (int cc = 0; cc < 16; ++cc) {
    int c = w * 16 + cc;
    csA[((size_t)hd * NC + c) * NHID + lane] = run; run += rA[cc];
    if (lane == 0) csAz[hd * NC + c] = runz;
    runz += rAz[cc];
  }
  run = bB; runz = bBz;
#pragma unroll
  for (int cc = 15; cc >= 0; --cc) {
    int c = w * 16 + cc;
    csB[((size_t)hd * NC + c) * NHID + lane] = run; run += rB[cc];
    if (lane == 0) csBz[hd * NC + c] = runz;
    runz += rBz[cc];
  }
}

// ---------------------------------------------------------------------------
// K6: layer-1 combine. Precomputed split-k; chunk bases + 16-term rebuild.
// ---------------------------------------------------------------------------
__global__ __launch_bounds__(256) void k_combine1(const float* __restrict__ ssrc,
                                                  const float* __restrict__ ts,
                                                  const int* __restrict__ perm,
                                                  const int* __restrict__ ksp,
                                                  const unsigned short* __restrict__ h1b,
                                                  const float* __restrict__ csA,
                                                  const float* __restrict__ csB,
                                                  const float* __restrict__ csAz,
                                                  const float* __restrict__ csBz,
                                                  unsigned short* __restrict__ xcb) {
  int hd = blockIdx.x >> 8;
  int base = (blockIdx.x & 255) * 16;
  int w = threadIdx.x >> 6, lane = threadIdx.x & 63;
  const float* tsh = ts + (size_t)hd * N;
  float tm = tsh[N - 1];
  for (int it = 0; it < 4; ++it) {
    int i = base + w * 4 + it;
    float s = ssrc[(size_t)hd * N + i];
    int k = ksp[(size_t)hd * N + i];
    int c = k >> 4; if (c > NC - 1) c = NC - 1;
    int c0 = c * 16;
    float v = s + tm;
    float m = fmaxf(v, ALPHA * v);
    float wA = expf(ALPHA * v - m), wB = expf(v - m);
    size_t cb = (size_t)hd * NC + c;
    float numA = csA[cb * NHID + lane];
    float numB = csB[cb * NHID + lane];
    float zA = csAz[cb], zB = csBz[cb];
    int r15 = lane & 15;
    float tvv = tsh[c0 + r15];
    int pvv = perm[(size_t)hd * N + c0 + r15];
    float ev = expf(((c0 + r15) < k ? ALPHA : 1.f) * (tvv - tm));
#pragma unroll
    for (int r = 0; r < 16; ++r) {
      float e = __shfl(ev, r);
      int p = __shfl(pvv, r);
      float hv = bf2f(h1b[((size_t)hd * N + p) * NHID + lane]);
      bool isA = (c0 + r) < k;
      if (isA) { numA += e * hv; zA += e; } else { numB += e * hv; zB += e; }
    }
    float Z = wA * zA + wB * zB;
    float f = (wA * numA + wB * numB) / Z;
    float e2 = f > 0.f ? f : expf(f) - 1.f;
    xcb[(size_t)i * (NHEADS * NHID) + hd * NHID + lane] = f2bf(e2);
  }
}

// ---------------------------------------------------------------------------
// K7: h2 = xc @ Wo via MFMA + fused layer-2 scores + deterministic global
// tmax. h2 stored bf16.
// ---------------------------------------------------------------------------
__global__ __launch_bounds__(256) void k_gemm2(const unsigned short* __restrict__ xcb,
                                               const unsigned short* __restrict__ Wt2,
                                               const float* __restrict__ ao,
                                               unsigned short* __restrict__ h2b,
                                               float* __restrict__ ssrc,
                                               float* __restrict__ sdst,
                                               unsigned* __restrict__ tmax2u) {
  const int t = threadIdx.x;
  const int w = t >> 6, lane = t & 63;
  const int lr = lane & 15, kg = lane >> 4;
  const int i0 = blockIdx.x * 64 + w * 16;
  __shared__ float sd[64];
  f32x4 acc = (f32x4){0.f, 0.f, 0.f, 0.f};
  const unsigned short* arow = xcb + (size_t)(i0 + lr) * NFEAT;
  const unsigned short* brow = Wt2 + (size_t)lr * NFEAT;
#pragma unroll
  for (int k0 = 0; k0 < NFEAT; k0 += 32) {
    bf16x8 af = __builtin_bit_cast(bf16x8, *(const uint4*)(arow + k0 + kg * 8));
    bf16x8 bv = __builtin_bit_cast(bf16x8, *(const uint4*)(brow + k0 + kg * 8));
    acc = __builtin_amdgcn_mfma_f32_16x16x32_bf16(af, bv, acc, 0, 0, 0);
  }
  float aS = ao[lr], aD = ao[16 + lr];
#pragma unroll
  for (int reg = 0; reg < 4; ++reg) {
    int row = i0 + kg * 4 + reg;
    h2b[(size_t)row * NCLASS + lr] = f2bf(acc[reg]);
    float ps = acc[reg] * aS, pd = acc[reg] * aD;
#pragma unroll
    for (int m = 1; m < 16; m <<= 1) { ps += __shfl_xor(ps, m); pd += __shfl_xor(pd, m); }
    if (lr == 0) {
      ssrc[row] = ps;
      sdst[row] = pd;
      sd[w * 16 + kg * 4 + reg] = pd;
    }
  }
  __syncthreads();
  if (t < 64) {
    float v = sd[t];
#pragma unroll
    for (int m = 32; m; m >>= 1) v = fmaxf(v, __shfl_xor(v, m));
    if (t == 0) atomicMax(tmax2u, mono(v));
  }
}

// ---------------------------------------------------------------------------
// K8a: layer-2 attention partials via MFMA. num = E @ H2 with E built
// in-register (fast exp + bf16 pack); H2 slice transposed in LDS
// (hsT[class][j], stride 520 -> 2-way banks = free). Z in fp32 (2 shfls).
// grid (N/64 row-blocks, JSPL) x 256 thr; wave = 16 rows x JLEN js.
// ---------------------------------------------------------------------------
__global__ __launch_bounds__(256) void k_attn2p(const float* __restrict__ ssrc,
                                                const float* __restrict__ t,
                                                const unsigned short* __restrict__ h2b,
                                                const unsigned* __restrict__ tmax2u,
                                                float* __restrict__ pnum,
                                                float* __restrict__ pz) {
  __shared__ float tl[JLEN];                    // 2 KB
  __shared__ unsigned short hsT[16 * HSTR];     // 16.25 KB, transposed h2
  int tid = threadIdx.x;
  int jb = blockIdx.y;
  if (tid < 128) {
    int i4 = tid * 4;
    *(float4*)(tl + i4) = *(const float4*)(t + jb * JLEN + i4);
  }
#pragma unroll
  for (int rep = 0; rep < 2; ++rep) {
    int j = rep * 256 + tid;
    const uint4* src = (const uint4*)(h2b + (size_t)(jb * JLEN + j) * NCLASS);
    uint4 a = src[0], b = src[1];
    unsigned short v[16];
    *(uint4*)v = a; *(uint4*)(v + 8) = b;
#pragma unroll
    for (int c = 0; c < 16; ++c) hsT[c * HSTR + j] = v[c];
  }
  __syncthreads();
  int w = tid >> 6, lane = tid & 63;
  int lr = lane & 15, kg = lane >> 4;
  int ib = blockIdx.x * 64 + w * 16;
  float tmax = unmono(*tmax2u);
  float s = ssrc[ib + lr];
  float v0 = s + tmax;
  float rowm = fmaxf(v0, ALPHA * v0);  // exact global row max (monotone LR)
  f32x4 acc = (f32x4){0.f, 0.f, 0.f, 0.f};
  float zpart = 0.f;
#pragma unroll
  for (int c = 0; c < JLEN / 32; ++c) {
    const float* tp = tl + c * 32 + kg * 8;
    float e[8];
#pragma unroll
    for (int m = 0; m < 8; ++m) {
      float v = s + tp[m];
      e[m] = __expf(fmaxf(v, ALPHA * v) - rowm);
      zpart += e[m];
    }
    unsigned pk[4];
#pragma unroll
    for (int p = 0; p < 4; ++p)
      pk[p] = ((unsigned)f2bf(e[2 * p + 1]) << 16) | (unsigned)f2bf(e[2 * p]);
    bf16x8 af = __builtin_bit_cast(bf16x8, *(uint4*)pk);
    bf16x8 bf = __builtin_bit_cast(bf16x8,
        *(const uint4*)(hsT + lr * HSTR + c * 32 + kg * 8));
    acc = __builtin_amdgcn_mfma_f32_16x16x32_bf16(af, bf, acc, 0, 0, 0);
  }
  // Z: sum the 4 k-group partials per row (lanes lr, lr+16, lr+32, lr+48)
  zpart += __shfl_xor(zpart, 16);
  zpart += __shfl_xor(zpart, 32);
  // D layout: col = lane&15 (class), row = (lane>>4)*4 + reg
#pragma unroll
  for (int reg = 0; reg < 4; ++reg)
    pnum[((size_t)jb * N + ib + kg * 4 + reg) * NCLASS + lr] = acc[reg];
  if (lane < 16) pz[(size_t)jb * N + ib + lane] = zpart;
}

// ---------------------------------------------------------------------------
// K8b: combine partials + ELU + log_softmax. 256 blocks x 256 thr
// (16 rows/block, 16 lanes/row).
// ---------------------------------------------------------------------------
__global__ __launch_bounds__(256) void k_attn2f(const float* __restrict__ pnum,
                                                const float* __restrict__ pz,
                                                float* __restrict__ out) {
  int g = threadIdx.x >> 4, cl = threadIdx.x & 15;
  int i = blockIdx.x * 16 + g;
  float nsum = 0.f, zsum = 0.f;
#pragma unroll
  for (int jb = 0; jb < JSPL; ++jb) {
    nsum += pnum[((size_t)jb * N + i) * NCLASS + cl];
    zsum += pz[(size_t)jb * N + i];
  }
  float o = nsum / zsum;
  o = o > 0.f ? o : expf(o) - 1.f;  // ELU
  float mo = o;
#pragma unroll
  for (int mk = 1; mk < 16; mk <<= 1) mo = fmaxf(mo, __shfl_xor(mo, mk, 16));
  float sum = expf(o - mo);
#pragma unroll
  for (int mk = 1; mk < 16; mk <<= 1) sum += __shfl_xor(sum, mk, 16);
  out[(size_t)i * NCLASS + cl] = o - mo - logf(sum);
}

// ---------------------------------------------------------------------------
extern "C" void kernel_launch(void* const* d_in, const int* in_sizes, int n_in,
                              void* d_out, int out_size, void* d_ws, size_t ws_size,
                              hipStream_t stream) {
  const float* x  = (const float*)d_in[0];
  const float* Wh = (const float*)d_in[1];
  const float* ah = (const float*)d_in[2];
  const float* Wo = (const float*)d_in[3];
  const float* ao = (const float*)d_in[4];
  float* out = (float*)d_out;

  char* base = (char*)d_ws;
  size_t off = 0;
  auto alloc_f = [&](size_t n) -> float* {
    float* p = (float*)(base + off);
    off = (off + n * sizeof(float) + 255) & ~(size_t)255;
    return p;
  };
  auto alloc_i = [&](size_t n) -> int* {
    int* p = (int*)(base + off);
    off = (off + n * sizeof(int) + 255) & ~(size_t)255;
    return p;
  };
  auto alloc_u16 = [&](size_t n) -> unsigned short* {
    unsigned short* p = (unsigned short*)(base + off);
    off = (off + n * sizeof(unsigned short) + 255) & ~(size_t)255;
    return p;
  };

  unsigned short* xbf = alloc_u16((size_t)N * NFEAT);
  unsigned short* Wt  = alloc_u16((size_t)NHEADS * NHID * NFEAT);
  unsigned short* Wt2 = alloc_u16((size_t)NCLASS * NFEAT);
  unsigned short* h1b = alloc_u16((size_t)NHEADS * N * NHID);
  float* ssrc1 = alloc_f((size_t)NHEADS * N);
  float* sdst1 = alloc_f((size_t)NHEADS * N);
  float* ts1   = alloc_f((size_t)NHEADS * N);
  int*   perm1 = alloc_i((size_t)NHEADS * N);
  int*   ksp1  = alloc_i((size_t)NHEADS * N);
  float* csA1  = alloc_f((size_t)NHEADS * NC * NHID);
  float* csB1  = alloc_f((size_t)NHEADS * NC * NHID);
  float* csAz1 = alloc_f(NHEADS * NC);
  float* csBz1 = alloc_f(NHEADS * NC);
  unsigned short* xcb = alloc_u16((size_t)N * NHEADS * NHID);
  unsigned short* h2b = alloc_u16((size_t)N * NCLASS);
  float* ssrc2 = alloc_f(N);
  float* sdst2 = alloc_f(N);
  unsigned* tmax2u = (unsigned*)alloc_i(1);
  float* pnum  = alloc_f((size_t)JSPL * N * NCLASS);
  float* pz    = alloc_f((size_t)JSPL * N);

  if (off > ws_size) return;

  hipLaunchKernelGGL(k_pack, dim3(2113), dim3(256), 0, stream, x, Wh, Wo, xbf, Wt, Wt2, tmax2u);

  // ---- Layer 1 ----
  hipLaunchKernelGGL(k_gemm_h, dim3(N / 128, NHEADS), dim3(256), 0, stream, xbf, Wt, ah, h1b, ssrc1, sdst1);
  hipLaunchKernelGGL(k_rank, dim3(64, NHEADS), dim3(256), 0, stream, sdst1, ssrc1, ts1, perm1, ksp1);
  hipLaunchKernelGGL(k_chunksum1, dim3(64, NHEADS), dim3(256), 0, stream, ts1, perm1, h1b, csA1, csB1, csAz1, csBz1);
  hipLaunchKernelGGL(k_chunkscan1, dim3(NHEADS), dim3(1024), 0, stream, csA1, csB1, csAz1, csBz1);
  hipLaunchKernelGGL(k_combine1, dim3(NHEADS * 256), dim3(256), 0, stream, ssrc1, ts1, perm1, ksp1, h1b, csA1, csB1, csAz1, csBz1, xcb);

  // ---- Layer 2 (MFMA direct attention) ----
  hipLaunchKernelGGL(k_gemm2, dim3(N / 64), dim3(256), 0, stream, xcb, Wt2, ao, h2b, ssrc2, sdst2, tmax2u);
  hipLaunchKernelGGL(k_attn2p, dim3(N / 64, JSPL), dim3(256), 0, stream, ssrc2, sdst2, h2b, tmax2u, pnum, pz);
  hipLaunchKernelGGL(k_attn2f, dim3(N / 16), dim3(256), 0, stream, pnum, pz, out);
}

// Round 16
// 105.721 us; speedup vs baseline: 1.9205x; 1.0158x over previous
//
#include <hip/hip_runtime.h>
#include <math.h>

#define N 4096
#define NFEAT 512
#define NHID 64
#define NCLASS 16
#define NHEADS 8
#define ALPHA 0.2f
#define NC 256   // chunks per head (16 rows each)
#define JSPL 8   // layer-2 j-split
#define JLEN (N / JSPL)   // 512
#define HSTR 520          // padded hsT row stride (ushorts); 2-way banks = free

typedef __attribute__((ext_vector_type(8))) short bf16x8;
typedef __attribute__((ext_vector_type(4))) float f32x4;

__device__ inline unsigned short f2bf(float f) {
  unsigned u = __float_as_uint(f);
  unsigned r = u + 0x7fffu + ((u >> 16) & 1u);  // RNE
  return (unsigned short)(r >> 16);
}
__device__ inline float bf2f(unsigned short u) {
  return __uint_as_float(((unsigned)u) << 16);
}
__device__ inline unsigned mono(float f) {
  unsigned u = __float_as_uint(f);
  return (u & 0x80000000u) ? ~u : (u | 0x80000000u);
}
__device__ inline float unmono(unsigned m) {
  return (m >> 31) ? __uint_as_float(m & 0x7FFFFFFFu) : __uint_as_float(~m);
}

// ---------------------------------------------------------------------------
// P0: pack. blocks [0,2048): x->bf16; [2048,2112): Wt=bf16(Wh^T);
// 2112: Wt2 + tmax2 init.
// ---------------------------------------------------------------------------
__global__ __launch_bounds__(256) void k_pack(const float* __restrict__ x,
                                              const float* __restrict__ Wh,
                                              const float* __restrict__ Wo,
                                              unsigned short* __restrict__ xb,
                                              unsigned short* __restrict__ Wt,
                                              unsigned short* __restrict__ Wt2,
                                              unsigned* __restrict__ tmax2u) {
  int b = blockIdx.x;
  if (b < 2048) {
    int i = (b * 256 + threadIdx.x) * 4;
    float4 v = *(const float4*)(x + i);
    ushort4 o;
    o.x = f2bf(v.x); o.y = f2bf(v.y); o.z = f2bf(v.z); o.w = f2bf(v.w);
    *(ushort4*)(xb + i) = o;
  } else if (b < 2112) {
    int idx = b - 2048;
    int kt = idx & 7, hd = idx >> 3;
    __shared__ float ld[64][65];
    const float* src = Wh + ((size_t)hd * NFEAT + kt * 64) * NHID;
    int r = threadIdx.x >> 2, c0 = (threadIdx.x & 3) * 16;
#pragma unroll
    for (int j = 0; j < 4; ++j) {
      float4 v = *(const float4*)(src + (size_t)r * NHID + c0 + j * 4);
      ld[r][c0 + j * 4 + 0] = v.x; ld[r][c0 + j * 4 + 1] = v.y;
      ld[r][c0 + j * 4 + 2] = v.z; ld[r][c0 + j * 4 + 3] = v.w;
    }
    __syncthreads();
    int n = threadIdx.x >> 2, kq = threadIdx.x & 3;
    unsigned short tmp[16];
#pragma unroll
    for (int j = 0; j < 16; ++j) tmp[j] = f2bf(ld[kq * 16 + j][n]);
    unsigned short* dst = Wt + ((size_t)hd * 64 + n) * NFEAT + kt * 64 + kq * 16;
    ((uint4*)dst)[0] = *(uint4*)tmp;
    ((uint4*)dst)[1] = *(uint4*)(tmp + 8);
  } else {
    for (int e = threadIdx.x; e < NFEAT * NCLASS; e += 256) {
      int n = e & 15, k = e >> 4;
      Wt2[(size_t)n * NFEAT + k] = f2bf(Wo[(size_t)k * NCLASS + n]);
    }
    if (threadIdx.x == 0) *tmax2u = 0u;  // mono(-inf)
  }
}

// ---------------------------------------------------------------------------
// K1: MFMA bf16 GEMM h = x @ Wh per head, 128x64 tile, 4 waves, fused scores.
// Staging via global_load_lds(16B) with pre-swizzled per-lane SOURCE address
// (LDS linear dest; read-side XOR unchanged). h stored bf16.
// ---------------------------------------------------------------------------
__global__ __launch_bounds__(256) void k_gemm_h(const unsigned short* __restrict__ xb,
                                                const unsigned short* __restrict__ Wt,
                                                const float* __restrict__ ah,
                                                unsigned short* __restrict__ h1b,
                                                float* __restrict__ ssrc,
                                                float* __restrict__ sdst) {
  const int hd = blockIdx.y;
  const int i0 = blockIdx.x * 128;
  const int t = threadIdx.x;
  const int w = t >> 6, lane = t & 63;
  const int lr = lane & 15, kg = lane >> 4;
  const int wm = (w & 1) * 64, wn = (w >> 1) * 32;
  __shared__ uint4 Als[128][4];
  __shared__ uint4 Bls[64][4];
  __shared__ float sredS[128][2];
  __shared__ float sredD[128][2];
  const unsigned short* xrow = xb + (size_t)i0 * NFEAT;
  const unsigned short* wrow = Wt + (size_t)hd * 64 * NFEAT;

  f32x4 acc[4][2];
#pragma unroll
  for (int a = 0; a < 4; ++a)
#pragma unroll
    for (int b = 0; b < 2; ++b) acc[a][b] = (f32x4){0.f, 0.f, 0.f, 0.f};

  // pre-swizzled source addressing for linear LDS dest (unit = 16B):
  //   LDS unit u holds source unit (u&3)^(row&3) of row u>>2.
  const int u0 = t, u1 = t + 256;                       // A units
  const int ra0 = u0 >> 2, sa0 = ((u0 & 3) ^ (ra0 & 3)) * 8;
  const int ra1 = u1 >> 2, sa1 = ((u1 & 3) ^ (ra1 & 3)) * 8;
  const int rb0 = t >> 2,  sb0 = ((t & 3) ^ (rb0 & 3)) * 8;   // B unit = t
  const int wbase = t & ~63;                            // wave-uniform

  for (int k0 = 0; k0 < NFEAT; k0 += 32) {
    __builtin_amdgcn_global_load_lds(
        (const __attribute__((address_space(1))) void*)(xrow + (size_t)ra0 * NFEAT + k0 + sa0),
        (__attribute__((address_space(3))) void*)((uint4*)Als + wbase), 16, 0, 0);
    __builtin_amdgcn_global_load_lds(
        (const __attribute__((address_space(1))) void*)(xrow + (size_t)ra1 * NFEAT + k0 + sa1),
        (__attribute__((address_space(3))) void*)((uint4*)Als + 256 + wbase), 16, 0, 0);
    __builtin_amdgcn_global_load_lds(
        (const __attribute__((address_space(1))) void*)(wrow + (size_t)rb0 * NFEAT + k0 + sb0),
        (__attribute__((address_space(3))) void*)((uint4*)Bls + wbase), 16, 0, 0);
    __syncthreads();
    bf16x8 af[4], bfv[2];
#pragma unroll
    for (int mb = 0; mb < 4; ++mb) {
      int row = wm + mb * 16 + lr;
      af[mb] = __builtin_bit_cast(bf16x8, Als[row][kg ^ (row & 3)]);
    }
#pragma unroll
    for (int nb = 0; nb < 2; ++nb) {
      int col = wn + nb * 16 + lr;
      bfv[nb] = __builtin_bit_cast(bf16x8, Bls[col][kg ^ (col & 3)]);
    }
#pragma unroll
    for (int mb = 0; mb < 4; ++mb)
#pragma unroll
      for (int nb = 0; nb < 2; ++nb)
        acc[mb][nb] = __builtin_amdgcn_mfma_f32_16x16x32_bf16(af[mb], bfv[nb], acc[mb][nb], 0, 0, 0);
    __syncthreads();
  }

  unsigned short* hout = h1b + ((size_t)hd * N + i0) * NHID;
#pragma unroll
  for (int mb = 0; mb < 4; ++mb)
#pragma unroll
    for (int nb = 0; nb < 2; ++nb) {
      int rbase = wm + mb * 16 + kg * 4;
      int col = wn + nb * 16 + lr;
#pragma unroll
      for (int reg = 0; reg < 4; ++reg)
        hout[(size_t)(rbase + reg) * NHID + col] = f2bf(acc[mb][nb][reg]);
    }

  float aS[2], aD[2];
#pragma unroll
  for (int nb = 0; nb < 2; ++nb) {
    aS[nb] = ah[hd * 128 + wn + nb * 16 + lr];
    aD[nb] = ah[hd * 128 + 64 + wn + nb * 16 + lr];
  }
#pragma unroll
  for (int mb = 0; mb < 4; ++mb)
#pragma unroll
    for (int reg = 0; reg < 4; ++reg) {
      float ps = acc[mb][0][reg] * aS[0] + acc[mb][1][reg] * aS[1];
      float pd = acc[mb][0][reg] * aD[0] + acc[mb][1][reg] * aD[1];
#pragma unroll
      for (int m = 1; m < 16; m <<= 1) { ps += __shfl_xor(ps, m); pd += __shfl_xor(pd, m); }
      if (lr == 0) {
        int rl = wm + mb * 16 + kg * 4 + reg;
        sredS[rl][w >> 1] = ps;
        sredD[rl][w >> 1] = pd;
      }
    }
  __syncthreads();
  if (t < 128) {
    ssrc[(size_t)hd * N + i0 + t] = sredS[t][0] + sredS[t][1];
    sdst[(size_t)hd * N + i0 + t] = sredD[t][0] + sredD[t][1];
  }
}

// ---------------------------------------------------------------------------
// K4: ballot rank + per-row split-k (layer 1 only). u32 keys.
// ---------------------------------------------------------------------------
__global__ __launch_bounds__(256) void k_rank(const float* __restrict__ t,
                                              const float* __restrict__ ssrc,
                                              float* __restrict__ ts,
                                              int* __restrict__ perm,
                                              int* __restrict__ ksp) {
  int hd = blockIdx.y;
  const float* th = t + (size_t)hd * N;
  __shared__ unsigned skey[N];
  int tid = threadIdx.x;
  for (int i = tid; i < N; i += 256)
    skey[i] = (mono(th[i]) & 0xFFFFF000u) | (unsigned)i;
  __syncthreads();
  int wv = tid >> 6, lane = tid & 63;
  int jbase = blockIdx.x * 64 + wv * 16;
  unsigned kj[16], qk[16];
  int cnt[16], cq[16];
#pragma unroll
  for (int jj = 0; jj < 16; ++jj) {
    kj[jj] = skey[jbase + jj];
    qk[jj] = (mono(-ssrc[(size_t)hd * N + jbase + jj]) & 0xFFFFF000u) | 0xFFFu;
    cnt[jj] = 0; cq[jj] = 0;
  }
  for (int c = 0; c < N; c += 64) {
    unsigned key = skey[c + lane];
#pragma unroll
    for (int jj = 0; jj < 16; ++jj) {
      cnt[jj] += __popcll(__ballot(key < kj[jj]));
      cq[jj]  += __popcll(__ballot(key < qk[jj]));
    }
  }
  int myc = 0, myq = 0;
#pragma unroll
  for (int jj = 0; jj < 16; ++jj)
    if (lane == jj) { myc = cnt[jj]; myq = cq[jj]; }
  if (lane < 16) {
    int j = jbase + lane;
    ts[(size_t)hd * N + myc] = th[j];
    perm[(size_t)hd * N + myc] = j;
    ksp[(size_t)hd * N + j] = myq;
  }
}

// ---------------------------------------------------------------------------
// K5a: chunksum layer 1 (wide grid for the gather). One wave per 16-row
// chunk; grid (64, 8) x 256 thr = 2048 waves.
// ---------------------------------------------------------------------------
__global__ __launch_bounds__(256) void k_chunksum1(const float* __restrict__ ts,
                                                   const int* __restrict__ perm,
                                                   const unsigned short* __restrict__ h1b,
                                                   float* __restrict__ csA,
                                                   float* __restrict__ csB,
                                                   float* __restrict__ csAz,
                                                   float* __restrict__ csBz) {
  int hd = blockIdx.y, lane = threadIdx.x & 63;
  int c = blockIdx.x * 4 + (threadIdx.x >> 6);
  int r0 = c * 16;
  float tm = ts[(size_t)hd * N + N - 1];
  float tvv = ts[(size_t)hd * N + r0 + (lane & 15)];
  float ev = expf((lane < 16 ? ALPHA : 1.f) * (tvv - tm));
  int pvv = perm[(size_t)hd * N + r0 + (lane & 15)];
  float sA = 0.f, sB = 0.f, zA = 0.f, zB = 0.f;
#pragma unroll
  for (int r = 0; r < 16; ++r) {
    float eA = __shfl(ev, r);
    float eB = __shfl(ev, 16 + r);
    int p = __shfl(pvv, r);
    float hv = bf2f(h1b[((size_t)hd * N + p) * NHID + lane]);
    sA += eA * hv; sB += eB * hv; zA += eA; zB += eB;
  }
  csA[((size_t)hd * NC + c) * NHID + lane] = sA;
  csB[((size_t)hd * NC + c) * NHID + lane] = sB;
  if (lane == 0) { csAz[hd * NC + c] = zA; csBz[hd * NC + c] = zB; }
}

// ---------------------------------------------------------------------------
// K5b: scan-only layer 1 (narrow; no gather). 8 blocks x 1024 thr.
// ---------------------------------------------------------------------------
__global__ __launch_bounds__(1024) void k_chunkscan1(float* __restrict__ csA,
                                                     float* __restrict__ csB,
                                                     float* __restrict__ csAz,
                                                     float* __restrict__ csBz) {
  int hd = blockIdx.x;
  int t = threadIdx.x, w = t >> 6, lane = t & 63;
  __shared__ float pA[16][64], pB[16][64];
  __shared__ float pAz[16], pBz[16];
  float rA[16], rB[16], rAz[16], rBz[16];
#pragma unroll
  for (int cc = 0; cc < 16; ++cc) {
    int c = w * 16 + cc;
    rA[cc] = csA[((size_t)hd * NC + c) * NHID + lane];
    rB[cc] = csB[((size_t)hd * NC + c) * NHID + lane];
    rAz[cc] = csAz[hd * NC + c];
    rBz[cc] = csBz[hd * NC + c];
  }
  float tA = 0.f, tB = 0.f, tAz = 0.f, tBz = 0.f;
#pragma unroll
  for (int cc = 0; cc < 16; ++cc) { tA += rA[cc]; tB += rB[cc]; tAz += rAz[cc]; tBz += rBz[cc]; }
  pA[w][lane] = tA; pB[w][lane] = tB;
  if (lane == 0) { pAz[w] = tAz; pBz[w] = tBz; }
  __syncthreads();
  float bA = 0.f, bAz = 0.f, bB = 0.f, bBz = 0.f;
  for (int w2 = 0; w2 < w; ++w2) { bA += pA[w2][lane]; bAz += pAz[w2]; }
  for (int w2 = w + 1; w2 < 16; ++w2) { bB += pB[w2][lane]; bBz += pBz[w2]; }
  float run = bA, runz = bAz;
#pragma unroll
  for (int cc = 0; cc < 16; ++cc) {
    int c = w * 16 + cc;
    csA[((size_t)hd * NC + c) * NHID + lane] = run; run += rA[cc];
    if (lane == 0) csAz[hd * NC + c] = runz;
    runz += rAz[cc];
  }
  run = bB; runz = bBz;
#pragma unroll
  for (int cc = 15; cc >= 0; --cc) {
    int c = w * 16 + cc;
    csB[((size_t)hd * NC + c) * NHID + lane] = run; run += rB[cc];
    if (lane == 0) csBz[hd * NC + c] = runz;
    runz += rBz[cc];
  }
}

// ---------------------------------------------------------------------------
// K6: layer-1 combine. Precomputed split-k; chunk bases + 16-term rebuild.
// ---------------------------------------------------------------------------
__global__ __launch_bounds__(256) void k_combine1(const float* __restrict__ ssrc,
                                                  const float* __restrict__ ts,
                                                  const int* __restrict__ perm,
                                                  const int* __restrict__ ksp,
                                                  const unsigned short* __restrict__ h1b,
                                                  const float* __restrict__ csA,
                                                  const float* __restrict__ csB,
                                                  const float* __restrict__ csAz,
                                                  const float* __restrict__ csBz,
                                                  unsigned short* __restrict__ xcb) {
  int hd = blockIdx.x >> 8;
  int base = (blockIdx.x & 255) * 16;
  int w = threadIdx.x >> 6, lane = threadIdx.x & 63;
  const float* tsh = ts + (size_t)hd * N;
  float tm = tsh[N - 1];
  for (int it = 0; it < 4; ++it) {
    int i = base + w * 4 + it;
    float s = ssrc[(size_t)hd * N + i];
    int k = ksp[(size_t)hd * N + i];
    int c = k >> 4; if (c > NC - 1) c = NC - 1;
    int c0 = c * 16;
    float v = s + tm;
    float m = fmaxf(v, ALPHA * v);
    float wA = expf(ALPHA * v - m), wB = expf(v - m);
    size_t cb = (size_t)hd * NC + c;
    float numA = csA[cb * NHID + lane];
    float numB = csB[cb * NHID + lane];
    float zA = csAz[cb], zB = csBz[cb];
    int r15 = lane & 15;
    float tvv = tsh[c0 + r15];
    int pvv = perm[(size_t)hd * N + c0 + r15];
    float ev = expf(((c0 + r15) < k ? ALPHA : 1.f) * (tvv - tm));
#pragma unroll
    for (int r = 0; r < 16; ++r) {
      float e = __shfl(ev, r);
      int p = __shfl(pvv, r);
      float hv = bf2f(h1b[((size_t)hd * N + p) * NHID + lane]);
      bool isA = (c0 + r) < k;
      if (isA) { numA += e * hv; zA += e; } else { numB += e * hv; zB += e; }
    }
    float Z = wA * zA + wB * zB;
    float f = (wA * numA + wB * numB) / Z;
    float e2 = f > 0.f ? f : expf(f) - 1.f;
    xcb[(size_t)i * (NHEADS * NHID) + hd * NHID + lane] = f2bf(e2);
  }
}

// ---------------------------------------------------------------------------
// K7: h2 = xc @ Wo via MFMA + fused layer-2 scores + deterministic global
// tmax. h2 stored bf16.
// ---------------------------------------------------------------------------
__global__ __launch_bounds__(256) void k_gemm2(const unsigned short* __restrict__ xcb,
                                               const unsigned short* __restrict__ Wt2,
                                               const float* __restrict__ ao,
                                               unsigned short* __restrict__ h2b,
                                               float* __restrict__ ssrc,
                                               float* __restrict__ sdst,
                                               unsigned* __restrict__ tmax2u) {
  const int t = threadIdx.x;
  const int w = t >> 6, lane = t & 63;
  const int lr = lane & 15, kg = lane >> 4;
  const int i0 = blockIdx.x * 64 + w * 16;
  __shared__ float sd[64];
  f32x4 acc = (f32x4){0.f, 0.f, 0.f, 0.f};
  const unsigned short* arow = xcb + (size_t)(i0 + lr) * NFEAT;
  const unsigned short* brow = Wt2 + (size_t)lr * NFEAT;
#pragma unroll
  for (int k0 = 0; k0 < NFEAT; k0 += 32) {
    bf16x8 af = __builtin_bit_cast(bf16x8, *(const uint4*)(arow + k0 + kg * 8));
    bf16x8 bv = __builtin_bit_cast(bf16x8, *(const uint4*)(brow + k0 + kg * 8));
    acc = __builtin_amdgcn_mfma_f32_16x16x32_bf16(af, bv, acc, 0, 0, 0);
  }
  float aS = ao[lr], aD = ao[16 + lr];
#pragma unroll
  for (int reg = 0; reg < 4; ++reg) {
    int row = i0 + kg * 4 + reg;
    h2b[(size_t)row * NCLASS + lr] = f2bf(acc[reg]);
    float ps = acc[reg] * aS, pd = acc[reg] * aD;
#pragma unroll
    for (int m = 1; m < 16; m <<= 1) { ps += __shfl_xor(ps, m); pd += __shfl_xor(pd, m); }
    if (lr == 0) {
      ssrc[row] = ps;
      sdst[row] = pd;
      sd[w * 16 + kg * 4 + reg] = pd;
    }
  }
  __syncthreads();
  if (t < 64) {
    float v = sd[t];
#pragma unroll
    for (int m = 32; m; m >>= 1) v = fmaxf(v, __shfl_xor(v, m));
    if (t == 0) atomicMax(tmax2u, mono(v));
  }
}

// ---------------------------------------------------------------------------
// K8a: layer-2 attention partials via MFMA. num = E @ H2 with E built
// in-register (fast exp + bf16 pack); H2 slice transposed in LDS
// (hsT[class][j], stride 520 -> 2-way banks = free). Z in fp32 (2 shfls).
// grid (N/64 row-blocks, JSPL) x 256 thr; wave = 16 rows x JLEN js.
// ---------------------------------------------------------------------------
__global__ __launch_bounds__(256) void k_attn2p(const float* __restrict__ ssrc,
                                                const float* __restrict__ t,
                                                const unsigned short* __restrict__ h2b,
                                                const unsigned* __restrict__ tmax2u,
                                                float* __restrict__ pnum,
                                                float* __restrict__ pz) {
  __shared__ float tl[JLEN];                    // 2 KB
  __shared__ unsigned short hsT[16 * HSTR];     // 16.25 KB, transposed h2
  int tid = threadIdx.x;
  int jb = blockIdx.y;
  if (tid < 128) {
    int i4 = tid * 4;
    *(float4*)(tl + i4) = *(const float4*)(t + jb * JLEN + i4);
  }
#pragma unroll
  for (int rep = 0; rep < 2; ++rep) {
    int j = rep * 256 + tid;
    const uint4* src = (const uint4*)(h2b + (size_t)(jb * JLEN + j) * NCLASS);
    uint4 a = src[0], b = src[1];
    unsigned short v[16];
    *(uint4*)v = a; *(uint4*)(v + 8) = b;
#pragma unroll
    for (int c = 0; c < 16; ++c) hsT[c * HSTR + j] = v[c];
  }
  __syncthreads();
  int w = tid >> 6, lane = tid & 63;
  int lr = lane & 15, kg = lane >> 4;
  int ib = blockIdx.x * 64 + w * 16;
  float tmax = unmono(*tmax2u);
  float s = ssrc[ib + lr];
  float v0 = s + tmax;
  float rowm = fmaxf(v0, ALPHA * v0);  // exact global row max (monotone LR)
  f32x4 acc = (f32x4){0.f, 0.f, 0.f, 0.f};
  float zpart = 0.f;
#pragma unroll
  for (int c = 0; c < JLEN / 32; ++c) {
    const float* tp = tl + c * 32 + kg * 8;
    float e[8];
#pragma unroll
    for (int m = 0; m < 8; ++m) {
      float v = s + tp[m];
      e[m] = __expf(fmaxf(v, ALPHA * v) - rowm);
      zpart += e[m];
    }
    unsigned pk[4];
#pragma unroll
    for (int p = 0; p < 4; ++p)
      pk[p] = ((unsigned)f2bf(e[2 * p + 1]) << 16) | (unsigned)f2bf(e[2 * p]);
    bf16x8 af = __builtin_bit_cast(bf16x8, *(uint4*)pk);
    bf16x8 bf = __builtin_bit_cast(bf16x8,
        *(const uint4*)(hsT + lr * HSTR + c * 32 + kg * 8));
    acc = __builtin_amdgcn_mfma_f32_16x16x32_bf16(af, bf, acc, 0, 0, 0);
  }
  // Z: sum the 4 k-group partials per row (lanes lr, lr+16, lr+32, lr+48)
  zpart += __shfl_xor(zpart, 16);
  zpart += __shfl_xor(zpart, 32);
  // D layout: col = lane&15 (class), row = (lane>>4)*4 + reg
#pragma unroll
  for (int reg = 0; reg < 4; ++reg)
    pnum[((size_t)jb * N + ib + kg * 4 + reg) * NCLASS + lr] = acc[reg];
  if (lane < 16) pz[(size_t)jb * N + ib + lane] = zpart;
}

// ---------------------------------------------------------------------------
// K8b: combine partials + ELU + log_softmax. 256 blocks x 256 thr
// (16 rows/block, 16 lanes/row).
// ---------------------------------------------------------------------------
__global__ __launch_bounds__(256) void k_attn2f(const float* __restrict__ pnum,
                                                const float* __restrict__ pz,
                                                float* __restrict__ out) {
  int g = threadIdx.x >> 4, cl = threadIdx.x & 15;
  int i = blockIdx.x * 16 + g;
  float nsum = 0.f, zsum = 0.f;
#pragma unroll
  for (int jb = 0; jb < JSPL; ++jb) {
    nsum += pnum[((size_t)jb * N + i) * NCLASS + cl];
    zsum += pz[(size_t)jb * N + i];
  }
  float o = nsum / zsum;
  o = o > 0.f ? o : expf(o) - 1.f;  // ELU
  float mo = o;
#pragma unroll
  for (int mk = 1; mk < 16; mk <<= 1) mo = fmaxf(mo, __shfl_xor(mo, mk, 16));
  float sum = expf(o - mo);
#pragma unroll
  for (int mk = 1; mk < 16; mk <<= 1) sum += __shfl_xor(sum, mk, 16);
  out[(size_t)i * NCLASS + cl] = o - mo - logf(sum);
}

// ---------------------------------------------------------------------------
extern "C" void kernel_launch(void* const* d_in, const int* in_sizes, int n_in,
                              void* d_out, int out_size, void* d_ws, size_t ws_size,
                              hipStream_t stream) {
  const float* x  = (const float*)d_in[0];
  const float* Wh = (const float*)d_in[1];
  const float* ah = (const float*)d_in[2];
  const float* Wo = (const float*)d_in[3];
  const float* ao = (const float*)d_in[4];
  float* out = (float*)d_out;

  char* base = (char*)d_ws;
  size_t off = 0;
  auto alloc_f = [&](size_t n) -> float* {
    float* p = (float*)(base + off);
    off = (off + n * sizeof(float) + 255) & ~(size_t)255;
    return p;
  };
  auto alloc_i = [&](size_t n) -> int* {
    int* p = (int*)(base + off);
    off = (off + n * sizeof(int) + 255) & ~(size_t)255;
    return p;
  };
  auto alloc_u16 = [&](size_t n) -> unsigned short* {
    unsigned short* p = (unsigned short*)(base + off);
    off = (off + n * sizeof(unsigned short) + 255) & ~(size_t)255;
    return p;
  };

  unsigned short* xbf = alloc_u16((size_t)N * NFEAT);
  unsigned short* Wt  = alloc_u16((size_t)NHEADS * NHID * NFEAT);
  unsigned short* Wt2 = alloc_u16((size_t)NCLASS * NFEAT);
  unsigned short* h1b = alloc_u16((size_t)NHEADS * N * NHID);
  float* ssrc1 = alloc_f((size_t)NHEADS * N);
  float* sdst1 = alloc_f((size_t)NHEADS * N);
  float* ts1   = alloc_f((size_t)NHEADS * N);
  int*   perm1 = alloc_i((size_t)NHEADS * N);
  int*   ksp1  = alloc_i((size_t)NHEADS * N);
  float* csA1  = alloc_f((size_t)NHEADS * NC * NHID);
  float* csB1  = alloc_f((size_t)NHEADS * NC * NHID);
  float* csAz1 = alloc_f(NHEADS * NC);
  float* csBz1 = alloc_f(NHEADS * NC);
  unsigned short* xcb = alloc_u16((size_t)N * NHEADS * NHID);
  unsigned short* h2b = alloc_u16((size_t)N * NCLASS);
  float* ssrc2 = alloc_f(N);
  float* sdst2 = alloc_f(N);
  unsigned* tmax2u = (unsigned*)alloc_i(1);
  float* pnum  = alloc_f((size_t)JSPL * N * NCLASS);
  float* pz    = alloc_f((size_t)JSPL * N);

  if (off > ws_size) return;

  hipLaunchKernelGGL(k_pack, dim3(2113), dim3(256), 0, stream, x, Wh, Wo, xbf, Wt, Wt2, tmax2u);

  // ---- Layer 1 ----
  hipLaunchKernelGGL(k_gemm_h, dim3(N / 128, NHEADS), dim3(256), 0, stream, xbf, Wt, ah, h1b, ssrc1, sdst1);
  hipLaunchKernelGGL(k_rank, dim3(64, NHEADS), dim3(256), 0, stream, sdst1, ssrc1, ts1, perm1, ksp1);
  hipLaunchKernelGGL(k_chunksum1, dim3(64, NHEADS), dim3(256), 0, stream, ts1, perm1, h1b, csA1, csB1, csAz1, csBz1);
  hipLaunchKernelGGL(k_chunkscan1, dim3(NHEADS), dim3(1024), 0, stream, csA1, csB1, csAz1, csBz1);
  hipLaunchKernelGGL(k_combine1, dim3(NHEADS * 256), dim3(256), 0, stream, ssrc1, ts1, perm1, ksp1, h1b, csA1, csB1, csAz1, csBz1, xcb);

  // ---- Layer 2 (MFMA direct attention) ----
  hipLaunchKernelGGL(k_gemm2, dim3(N / 64), dim3(256), 0, stream, xcb, Wt2, ao, h2b, ssrc2, sdst2, tmax2u);
  hipLaunchKernelGGL(k_attn2p, dim3(N / 64, JSPL), dim3(256), 0, stream, ssrc2, sdst2, h2b, tmax2u, pnum, pz);
  hipLaunchKernelGGL(k_attn2f, dim3(N / 16), dim3(256), 0, stream, pnum, pz, out);
}